// Round 13
// baseline (1242.127 us; speedup 1.0000x reference)
//
#include <hip/hip_runtime.h>
#include <math.h>

#define S0 3600
#define S1 720
#define S2 144
#define S3 36
#define S4 9
#define NEGF (-1e30f)

// ---- workspace layout (bytes). Peak 74.72 MB (proven in rounds 2-12).
static constexpr size_t OFF_X0  = 0;                                    // f32 [3600*3600] = 51,840,000
static constexpr size_t OFF_M0B = (size_t)S0 * S0 * 4;                  // u32 bitfield    = 1,620,000
static constexpr size_t OFF_Y1  = OFF_M0B + 1620000;                    // f32 [720*720*10] @53,460,000
static constexpr size_t OFF_M1  = OFF_Y1 + (size_t)S1 * S1 * 10 * 4;    // u8  [720*720]    @74,196,000 (ends 74,714,400)
// aliased into dead x0 region (used from conv2 onward):
static constexpr size_t OFF_Y2  = 0;                                    // f32 [144*144*64]  = 5,308,416
static constexpr size_t OFF_M2  = OFF_Y2 + (size_t)S2 * S2 * 64 * 4;    // u8  [144*144]
static constexpr size_t OFF_Y3  = OFF_M2 + 20736;                       // f32 [36*36*128] @5,329,152
static constexpr size_t OFF_M3  = OFF_Y3 + (size_t)S3 * S3 * 128 * 4;   // u8  [36*36]     @5,992,704
static constexpr size_t OFF_Y4  = OFF_M3 + 1296;                        // f32 [9*9*256]   @5,994,000
static constexpr size_t OFF_H1  = OFF_Y4 + (size_t)S4 * S4 * 256 * 4;   // f32 [32]        @6,076,944
static constexpr size_t OFF_P4  = 6077200;                              // f32 [81*5*16*256] = 6,635,520 (ends 12.7 MB)

__device__ __forceinline__ float eluf(float x) { return x > 0.f ? x : expm1f(x); }
__device__ __forceinline__ void fma4(float4& a, float s, const float4& w) {
    a.x = fmaf(s, w.x, a.x); a.y = fmaf(s, w.y, a.y);
    a.z = fmaf(s, w.z, a.z); a.w = fmaf(s, w.w, a.w);
}

// ---- zero x0 at the active coordinates (replaces 51.8 MB memset) ------------
__global__ __launch_bounds__(256) void k_zero(const int* __restrict__ coords,
                                              float* __restrict__ x0, int P) {
    int i = blockIdx.x * 256 + threadIdx.x;
    if (i >= P) return;
    x0[coords[2 * i] * S0 + coords[2 * i + 1]] = 0.f;
}

// ---- scatter points onto dense grid -----------------------------------------
__global__ __launch_bounds__(256) void k_scatter(const int* __restrict__ coords,
                                                 const float* __restrict__ feats,
                                                 float* __restrict__ x0,
                                                 unsigned* __restrict__ m0b, int P) {
    int i = blockIdx.x * 256 + threadIdx.x;
    if (i >= P) return;
    int r = coords[2 * i], c = coords[2 * i + 1];
    int idx = r * S0 + c;
    atomicAdd(&x0[idx], feats[i]);
    atomicOr(&m0b[idx >> 5], 1u << (idx & 31));
}

// ---- layer 1: sparse conv 5x5 1->10 + ELU + maxpool5 (mask-bitfield-driven) -
__global__ __launch_bounds__(256) void k_l1(const float* __restrict__ x0,
                                            const unsigned* __restrict__ m0b,
                                            const float* __restrict__ w1,
                                            float* __restrict__ y1,
                                            unsigned char* __restrict__ m1) {
    __shared__ float w1s[250];
    int tid = threadIdx.x;
    if (tid < 250) w1s[tid] = w1[tid];
    __syncthreads();
    int t = blockIdx.x * 256 + tid;       // grid exact: 720*720 = 518400
    int pr = t / S1, pc = t % S1;
    int r0 = pr * 5 - 2, c0 = pc * 5 - 2; // 9x9 patch origin
    unsigned rows[9];
#pragma unroll
    for (int rr = 0; rr < 9; rr++) {
        unsigned bits = 0;
        int gr = r0 + rr;
        if (gr >= 0 && gr < S0) {
            int cs = c0 < 0 ? 0 : c0;
            int ce = c0 + 8 > S0 - 1 ? S0 - 1 : c0 + 8;
            int span = ce - cs;
            size_t i0 = (size_t)gr * S0 + cs;
            unsigned sh = (unsigned)(i0 & 31);
            unsigned long long two = (unsigned long long)m0b[i0 >> 5] >> sh;
            if ((int)sh + span >= 32)
                two |= (unsigned long long)m0b[(i0 >> 5) + 1] << (32 - sh);
            bits = (unsigned)(two & ((1u << (span + 1)) - 1));
            bits <<= (cs - c0);
        }
        rows[rr] = bits;
    }
    unsigned any25 = 0;
#pragma unroll
    for (int dy = 0; dy < 5; dy++) any25 |= (rows[2 + dy] >> 2) & 0x1Fu;
    float* yo = &y1[(size_t)t * 10];
    if (!any25) {
#pragma unroll
        for (int q = 0; q < 5; q++) ((float2*)yo)[q] = make_float2(0.f, 0.f);
        m1[t] = 0;
        return;
    }
    float2 mx[5];
#pragma unroll
    for (int q = 0; q < 5; q++) mx[q] = make_float2(NEGF, NEGF);
    for (int dy = 0; dy < 5; dy++) {
        unsigned crow = (rows[2 + dy] >> 2) & 0x1Fu;
        while (crow) {
            int dx = __ffs(crow) - 1; crow &= crow - 1;
            float2 acc[5];
#pragma unroll
            for (int q = 0; q < 5; q++) acc[q] = make_float2(0.f, 0.f);
#pragma unroll
            for (int ky = 0; ky < 5; ky++) {
                unsigned nrow = (rows[dy + ky] >> dx) & 0x1Fu;
                size_t rowbase = (size_t)(r0 + dy + ky) * S0 + (c0 + dx);
                while (nrow) {
                    int kx = __ffs(nrow) - 1; nrow &= nrow - 1;
                    float xv = x0[rowbase + kx];
                    const float2* wp = (const float2*)&w1s[(ky * 5 + kx) * 10];
#pragma unroll
                    for (int q = 0; q < 5; q++) {
                        float2 w = wp[q];
                        acc[q].x = fmaf(xv, w.x, acc[q].x);
                        acc[q].y = fmaf(xv, w.y, acc[q].y);
                    }
                }
            }
#pragma unroll
            for (int q = 0; q < 5; q++) {
                mx[q].x = fmaxf(mx[q].x, acc[q].x);
                mx[q].y = fmaxf(mx[q].y, acc[q].y);
            }
        }
    }
#pragma unroll
    for (int q = 0; q < 5; q++) {
        float2 o;
        o.x = eluf(mx[q].x); o.y = eluf(mx[q].y);
        ((float2*)yo)[q] = o;
    }
    m1[t] = 1;
}

// ---- layer 2: fused conv 5x5 10->64 (cell-gated) + ELU + maxpool5 -----------
// Block = 2x2 pool sites (72x72 grid, 256 thr; wave = one site).
__global__ __launch_bounds__(256) void k_l2(const float* __restrict__ y1,
                                            const unsigned char* __restrict__ m1,
                                            const float* __restrict__ w2,
                                            float* __restrict__ y2,
                                            unsigned char* __restrict__ m2) {
    __shared__ float win[196 * 12];      // 14x14 cells x 12 (10ch + 2 pad)
    __shared__ unsigned char sm[196];
    int b = blockIdx.x;                  // 0..5183
    int bpr = b / 72, bpc = b % 72;
    int r0 = bpr * 10 - 2, c0 = bpc * 10 - 2;
    int tid = threadIdx.x;
    if (tid < 196) {
        int gr = r0 + tid / 14, gc = c0 + tid % 14;
        bool ok = (gr >= 0 && gr < S1 && gc >= 0 && gc < S1);
        sm[tid] = ok ? m1[gr * S1 + gc] : (unsigned char)0;
        float* dst = &win[tid * 12];
        if (ok) {
            const float2* src = (const float2*)&y1[((size_t)gr * S1 + gc) * 10];
#pragma unroll
            for (int q = 0; q < 5; q++) ((float2*)dst)[q] = src[q];
        } else {
#pragma unroll
            for (int q = 0; q < 5; q++) ((float2*)dst)[q] = make_float2(0.f, 0.f);
        }
        dst[10] = 0.f; dst[11] = 0.f;
    }
    __syncthreads();
    int wave = tid >> 6;                 // 0..3 -> site (sr,sc) in 2x2
    int sr = wave >> 1, sc = wave & 1;
    int c = tid & 63;                    // out channel
    int so = sr * 5 * 14 + sc * 5;       // site origin within 14x14 window
    unsigned mbits = 0;
#pragma unroll
    for (int cell = 0; cell < 25; cell++) {
        if (sm[so + (2 + cell / 5) * 14 + (2 + cell % 5)]) mbits |= (1u << cell);
    }
    mbits = (unsigned)__builtin_amdgcn_readfirstlane((int)mbits);
    float acc[25];
#pragma unroll
    for (int i = 0; i < 25; i++) acc[i] = 0.f;
    for (int t5 = 0; t5 < 25; t5++) {
        float w[10];
#pragma unroll
        for (int ci = 0; ci < 10; ci++) w[ci] = w2[(t5 * 10 + ci) * 64 + c];
        int base = so + (t5 / 5) * 14 + (t5 % 5);
#pragma unroll
        for (int cell = 0; cell < 25; cell++) {
            if (mbits & (1u << cell)) {
                const float4* xp = (const float4*)&win[(base + (cell / 5) * 14 + (cell % 5)) * 12];
                float4 xa = xp[0], xb = xp[1], xc = xp[2];
                float a = acc[cell];
                a = fmaf(xa.x, w[0], a); a = fmaf(xa.y, w[1], a);
                a = fmaf(xa.z, w[2], a); a = fmaf(xa.w, w[3], a);
                a = fmaf(xb.x, w[4], a); a = fmaf(xb.y, w[5], a);
                a = fmaf(xb.z, w[6], a); a = fmaf(xb.w, w[7], a);
                a = fmaf(xc.x, w[8], a); a = fmaf(xc.y, w[9], a);
                acc[cell] = a;
            }
        }
    }
    float mx = NEGF;
#pragma unroll
    for (int cell = 0; cell < 25; cell++)
        if (mbits & (1u << cell)) mx = fmaxf(mx, acc[cell]);
    bool any = (mbits != 0);
    int site = (bpr * 2 + sr) * S2 + bpc * 2 + sc;
    y2[(size_t)site * 64 + c] = any ? eluf(mx) : 0.f;
    if (c == 0) m2[site] = any ? 1 : 0;
}

// ---- layer 3: fused conv 5x5 64->128 + ELU + maxpool4 -> 36^2 ---------------
// Block = 2x2 pool sites, 512 thr (8 waves; 2 waves/site): w3 L2 traffic
// 4.15 GB -> 1.04 GB AND 4 waves/SIMD occupancy (the R10 fix). Per-site
// thread = (co-quad 0..31, kq 0..3); tile 16 cells x 4 co x 16 ci
// (1 B LDS/FMA). kq pairs folded by shfl_xor(32); cross-wave via 32 KB LDS.
// __launch_bounds__(512,4) pins VGPR <= 128 (occupancy cliff at 128).
__global__ __launch_bounds__(512, 4) void k_l3(const float* __restrict__ y2,
                                               const unsigned char* __restrict__ m2,
                                               const float* __restrict__ w3,
                                               float* __restrict__ y3,
                                               unsigned char* __restrict__ m3) {
    __shared__ float win[12 * 12 * 64];   // 36,864 B
    __shared__ float xpart[4][16][128];   // 32,768 B  [site][cell][co]
    __shared__ unsigned char sm[64];      // 8x8 local cell mask
    int b = blockIdx.x;                   // 0..323 (18x18 supersites)
    int bpr = b / 18, bpc = b % 18;
    int r0 = bpr * 8 - 2, c0 = bpc * 8 - 2;
    int tid = threadIdx.x;
    float4* win4 = (float4*)win;
    for (int k = tid; k < 2304; k += 512) {
        int cellk = k >> 4, q = k & 15;
        int rr = cellk / 12, cc = cellk % 12;
        int gr = r0 + rr, gc = c0 + cc;
        float4 v = make_float4(0.f, 0.f, 0.f, 0.f);
        if (gr >= 0 && gr < S2 && gc >= 0 && gc < S2)
            v = ((const float4*)y2)[((size_t)gr * S2 + gc) * 16 + q];
        win4[k] = v;
    }
    if (tid < 64) {
        int lr = tid >> 3, lc = tid & 7;
        sm[tid] = m2[(bpr * 8 + lr) * S2 + bpc * 8 + lc];
    }
    __syncthreads();
    int site = tid >> 7;                  // 0..3
    int sr = site >> 1, sc = site & 1;
    int ts = tid & 127;                   // within-site thread
    int cog = ts & 31;                    // co = cog*4 .. +3
    int kq = ts >> 5;                     // ci quarter (0,1 in wave A; 2,3 in wave B)
    float4 acc[16];
#pragma unroll
    for (int i = 0; i < 16; i++) acc[i] = make_float4(0.f, 0.f, 0.f, 0.f);
#pragma unroll 1
    for (int ky = 0; ky < 5; ky++) {
#pragma unroll 1
        for (int kx = 0; kx < 5; kx++) {
            int t5 = ky * 5 + kx;
            const float4* wb = (const float4*)&w3[(size_t)(t5 * 64 + kq * 16) * 128 + cog * 4];
#pragma unroll
            for (int j = 0; j < 4; j++) {
                float4 w0 = wb[(j * 4 + 0) * 32];
                float4 w1 = wb[(j * 4 + 1) * 32];
                float4 w2v = wb[(j * 4 + 2) * 32];
                float4 w3v = wb[(j * 4 + 3) * 32];
                int xo = kq * 4 + j;
#pragma unroll
                for (int cr = 0; cr < 4; cr++) {
                    int rowb = ((sr * 4 + cr + ky) * 12 + sc * 4 + kx) * 16 + xo;
#pragma unroll
                    for (int cc2 = 0; cc2 < 4; cc2++) {
                        float4 xv = win4[rowb + cc2 * 16];
                        int cell = cr * 4 + cc2;
                        fma4(acc[cell], xv.x, w0);
                        fma4(acc[cell], xv.y, w1);
                        fma4(acc[cell], xv.z, w2v);
                        fma4(acc[cell], xv.w, w3v);
                    }
                }
            }
        }
    }
    // fold kq pairs within each wave (lanes differ by 32): waveA -> kq0+kq1,
    // waveB -> kq2+kq3
#pragma unroll
    for (int cell = 0; cell < 16; cell++) {
        acc[cell].x += __shfl_xor(acc[cell].x, 32, 64);
        acc[cell].y += __shfl_xor(acc[cell].y, 32, 64);
        acc[cell].z += __shfl_xor(acc[cell].z, 32, 64);
        acc[cell].w += __shfl_xor(acc[cell].w, 32, 64);
    }
    if (kq == 2) {
#pragma unroll
        for (int cell = 0; cell < 16; cell++)
            *(float4*)&xpart[site][cell][cog * 4] = acc[cell];
    }
    __syncthreads();
    if (kq == 0) {
        bool any = false;
#pragma unroll
        for (int cr = 0; cr < 4; cr++)
#pragma unroll
            for (int cc2 = 0; cc2 < 4; cc2++)
                any |= (sm[(sr * 4 + cr) * 8 + sc * 4 + cc2] != 0);
        float4 mv = make_float4(NEGF, NEGF, NEGF, NEGF);
#pragma unroll
        for (int cr = 0; cr < 4; cr++) {
#pragma unroll
            for (int cc2 = 0; cc2 < 4; cc2++) {
                if (sm[(sr * 4 + cr) * 8 + sc * 4 + cc2]) {
                    int cell = cr * 4 + cc2;
                    float4 lo = acc[cell];
                    float4 hi = *(float4*)&xpart[site][cell][cog * 4];
                    float4 v;
                    v.x = lo.x + hi.x; v.y = lo.y + hi.y;
                    v.z = lo.z + hi.z; v.w = lo.w + hi.w;
                    mv.x = fmaxf(mv.x, v.x); mv.y = fmaxf(mv.y, v.y);
                    mv.z = fmaxf(mv.z, v.z); mv.w = fmaxf(mv.w, v.w);
                }
            }
        }
        int siteg = (bpr * 2 + sr) * S3 + bpc * 2 + sc;
        float4 o;
        o.x = any ? eluf(mv.x) : 0.f; o.y = any ? eluf(mv.y) : 0.f;
        o.z = any ? eluf(mv.z) : 0.f; o.w = any ? eluf(mv.w) : 0.f;
        *(float4*)&y3[(size_t)siteg * 128 + cog * 4] = o;
        if (cog == 0) m3[siteg] = any ? 1 : 0;
    }
}

// ---- layer 4 conv, K-split over ky: block = (pool cell, ky) -----------------
__global__ __launch_bounds__(256) void k_l4(const float* __restrict__ y3,
                                            const float* __restrict__ w4,
                                            float* __restrict__ part) {
    __shared__ float win[4 * 8 * 128];  // 16 KB
    int b = blockIdx.x;                  // 0..404
    int p = b / 5, ky = b % 5;
    int ppr = p / S4, ppc = p % S4;
    int r0 = ppr * 4 - 2 + ky, c0 = ppc * 4 - 2;
    int tid = threadIdx.x;
    float4* win4 = (float4*)win;
    for (int k = tid; k < 1024; k += 256) {
        int cellk = k >> 5, q = k & 31;  // cellk = rr*8+cc, rr 0..3
        int gr = r0 + (cellk >> 3), gc = c0 + (cellk & 7);
        float4 v = make_float4(0.f, 0.f, 0.f, 0.f);
        if (gr >= 0 && gr < S3 && gc >= 0 && gc < S3)
            v = ((const float4*)y3)[((size_t)gr * S3 + gc) * 32 + q];
        win4[k] = v;
    }
    __syncthreads();
    int cq = tid & 63, pr = tid >> 6;    // co-quad 0..63, cell-row 0..3
    int co4 = cq * 4;
    float4 acc[4];
#pragma unroll
    for (int i = 0; i < 4; i++) acc[i] = make_float4(0.f, 0.f, 0.f, 0.f);
#pragma unroll 1
    for (int kx = 0; kx < 5; kx++) {
        int rowbase = pr * 8 + kx;                           // + pc
        const float4* wq = (const float4*)&w4[(size_t)((ky * 5 + kx) * 128) * 256 + co4];
#pragma unroll 4
        for (int ci4 = 0; ci4 < 32; ci4++) {
            float4 xv0 = win4[(rowbase + 0) * 32 + ci4];
            float4 xv1 = win4[(rowbase + 1) * 32 + ci4];
            float4 xv2 = win4[(rowbase + 2) * 32 + ci4];
            float4 xv3 = win4[(rowbase + 3) * 32 + ci4];
            float4 w0 = wq[(ci4 * 4 + 0) * 64];
            float4 w1 = wq[(ci4 * 4 + 1) * 64];
            float4 w2v = wq[(ci4 * 4 + 2) * 64];
            float4 w3v = wq[(ci4 * 4 + 3) * 64];
            fma4(acc[0], xv0.x, w0); fma4(acc[0], xv0.y, w1); fma4(acc[0], xv0.z, w2v); fma4(acc[0], xv0.w, w3v);
            fma4(acc[1], xv1.x, w0); fma4(acc[1], xv1.y, w1); fma4(acc[1], xv1.z, w2v); fma4(acc[1], xv1.w, w3v);
            fma4(acc[2], xv2.x, w0); fma4(acc[2], xv2.y, w1); fma4(acc[2], xv2.z, w2v); fma4(acc[2], xv2.w, w3v);
            fma4(acc[3], xv3.x, w0); fma4(acc[3], xv3.y, w1); fma4(acc[3], xv3.z, w2v); fma4(acc[3], xv3.w, w3v);
        }
    }
#pragma unroll
    for (int pc = 0; pc < 4; pc++) {
        int cell = pr * 4 + pc;
        *(float4*)&part[(((size_t)p * 5 + ky) * 16 + cell) * 256 + co4] = acc[pc];
    }
}

// ---- layer 4 reduce K-partials + ELU + maxpool4 -> 9^2 ----------------------
__global__ __launch_bounds__(256) void k_p4(const float* __restrict__ part,
                                            const unsigned char* __restrict__ m3,
                                            float* __restrict__ y4) {
    int p = blockIdx.x;                  // 0..80
    int co = threadIdx.x;                // 0..255
    int ppr = p / S4, ppc = p % S4;
    float mx = NEGF;
    bool any = false;
    for (int cell = 0; cell < 16; cell++) {
        int site = (ppr * 4 + (cell >> 2)) * S3 + ppc * 4 + (cell & 3);
        if (!m3[site]) continue;
        any = true;
        float s = 0.f;
#pragma unroll
        for (int ky = 0; ky < 5; ky++)
            s += part[(((size_t)p * 5 + ky) * 16 + cell) * 256 + co];
        mx = fmaxf(mx, s);
    }
    y4[(size_t)p * 256 + co] = any ? eluf(mx) : 0.f;
}

// ---- fc1 (deterministic): 32 blocks, block j computes h1[j] -----------------
__global__ __launch_bounds__(256) void k_fc1(const float* __restrict__ y4,
                                             const float* __restrict__ fc1_w,
                                             float* __restrict__ h1) {
    __shared__ float part[256];
    int j = blockIdx.x;                    // 0..31
    int tid = threadIdx.x;
    float s = 0.f;
    for (int i = tid; i < 256 * 81; i += 256) {
        int c = i / 81, rem = i % 81;      // NCHW flatten: i = c*81 + h*9 + w
        s = fmaf(y4[(size_t)rem * 256 + c], fc1_w[(size_t)i * 32 + j], s);
    }
    part[tid] = s;
    __syncthreads();
    for (int off = 128; off > 0; off >>= 1) {
        if (tid < off) part[tid] += part[tid + off];
        __syncthreads();
    }
    if (tid == 0) h1[j] = part[0];
}

// ---- fc2 + softmax ----------------------------------------------------------
__global__ __launch_bounds__(64) void k_fc2(const float* __restrict__ h1,
                                            const float* __restrict__ fc1_b,
                                            const float* __restrict__ fc2_w,
                                            const float* __restrict__ fc2_b,
                                            float* __restrict__ out) {
    __shared__ float hv[32];
    __shared__ float lg[5];
    int tid = threadIdx.x;
    if (tid < 32) hv[tid] = eluf(h1[tid] + fc1_b[tid]);
    __syncthreads();
    if (tid < 5) {
        float s = fc2_b[tid];
        for (int j = 0; j < 32; j++) s = fmaf(hv[j], fc2_w[j * 5 + tid], s);
        lg[tid] = s;
    }
    __syncthreads();
    if (tid == 0) {
        float m = lg[0];
        for (int k = 1; k < 5; k++) m = fmaxf(m, lg[k]);
        float e[5], sum = 0.f;
        for (int k = 0; k < 5; k++) { e[k] = expf(lg[k] - m); sum += e[k]; }
        for (int k = 0; k < 5; k++) out[k] = e[k] / sum;
    }
}

extern "C" void kernel_launch(void* const* d_in, const int* in_sizes, int n_in,
                              void* d_out, int out_size, void* d_ws, size_t ws_size,
                              hipStream_t stream) {
    const int* coords = (const int*)d_in[0];
    const float* feats = (const float*)d_in[1];
    const float* w1 = (const float*)d_in[2];
    const float* w2 = (const float*)d_in[3];
    const float* w3 = (const float*)d_in[4];
    const float* w4 = (const float*)d_in[5];
    const float* fc1w = (const float*)d_in[6];
    const float* fc1b = (const float*)d_in[7];
    const float* fc2w = (const float*)d_in[8];
    const float* fc2b = (const float*)d_in[9];
    float* out = (float*)d_out;
    char* ws = (char*)d_ws;
    float* x0 = (float*)(ws + OFF_X0);
    unsigned* m0b = (unsigned*)(ws + OFF_M0B);
    float* y1 = (float*)(ws + OFF_Y1);
    unsigned char* m1g = (unsigned char*)(ws + OFF_M1);
    float* y2 = (float*)(ws + OFF_Y2);
    unsigned char* m2g = (unsigned char*)(ws + OFF_M2);
    float* y3 = (float*)(ws + OFF_Y3);
    unsigned char* m3g = (unsigned char*)(ws + OFF_M3);
    float* y4 = (float*)(ws + OFF_Y4);
    float* h1 = (float*)(ws + OFF_H1);
    float* p4 = (float*)(ws + OFF_P4);
    int P = in_sizes[1];

    // zero only the mask bitfield (1.62 MB); x0 zeroed sparsely by k_zero.
    hipMemsetAsync(ws + OFF_M0B, 0, 1620000, stream);
    k_zero<<<(P + 255) / 256, 256, 0, stream>>>(coords, x0, P);
    k_scatter<<<(P + 255) / 256, 256, 0, stream>>>(coords, feats, x0, m0b, P);
    k_l1<<<(S1 * S1) / 256, 256, 0, stream>>>(x0, m0b, w1, y1, m1g);
    k_l2<<<72 * 72, 256, 0, stream>>>(y1, m1g, w2, y2, m2g);
    k_l3<<<18 * 18, 512, 0, stream>>>(y2, m2g, w3, y3, m3g);
    k_l4<<<S4 * S4 * 5, 256, 0, stream>>>(y3, w4, p4);
    k_p4<<<S4 * S4, 256, 0, stream>>>(p4, m3g, y4);
    k_fc1<<<32, 256, 0, stream>>>(y4, fc1w, h1);
    k_fc2<<<1, 64, 0, stream>>>(h1, fc1b, fc2w, fc2b, out);
}

// Round 14
// 496.062 us; speedup vs baseline: 2.5040x; 2.5040x over previous
//
#include <hip/hip_runtime.h>
#include <math.h>

#define S0 3600
#define S1 720
#define S2 144
#define S3 36
#define S4 9
#define NEGF (-1e30f)

// ---- workspace layout (bytes). Peak 74.72 MB (proven in rounds 2-13).
static constexpr size_t OFF_X0  = 0;                                    // f32 [3600*3600] = 51,840,000
static constexpr size_t OFF_M0B = (size_t)S0 * S0 * 4;                  // u32 bitfield    = 1,620,000
static constexpr size_t OFF_Y1  = OFF_M0B + 1620000;                    // f32 [720*720*10] @53,460,000
static constexpr size_t OFF_M1  = OFF_Y1 + (size_t)S1 * S1 * 10 * 4;    // u8  [720*720]    @74,196,000 (ends 74,714,400)
// aliased into dead x0 region (used from conv2 onward):
static constexpr size_t OFF_Y2  = 0;                                    // f32 [144*144*64]  = 5,308,416
static constexpr size_t OFF_M2  = OFF_Y2 + (size_t)S2 * S2 * 64 * 4;    // u8  [144*144]
static constexpr size_t OFF_Y3  = OFF_M2 + 20736;                       // f32 [36*36*128] @5,329,152
static constexpr size_t OFF_M3  = OFF_Y3 + (size_t)S3 * S3 * 128 * 4;   // u8  [36*36]     @5,992,704
static constexpr size_t OFF_Y4  = OFF_M3 + 1296;                        // f32 [9*9*256]   @5,994,000
static constexpr size_t OFF_H1  = OFF_Y4 + (size_t)S4 * S4 * 256 * 4;   // f32 [32]        @6,076,944
static constexpr size_t OFF_P4  = 6077200;                              // f32 [81*5*16*256] = 6,635,520 (ends 12.7 MB)

__device__ __forceinline__ float eluf(float x) { return x > 0.f ? x : expm1f(x); }
__device__ __forceinline__ void fma4(float4& a, float s, const float4& w) {
    a.x = fmaf(s, w.x, a.x); a.y = fmaf(s, w.y, a.y);
    a.z = fmaf(s, w.z, a.z); a.w = fmaf(s, w.w, a.w);
}

// ---- zero x0 at the active coordinates (replaces 51.8 MB memset) ------------
__global__ __launch_bounds__(256) void k_zero(const int* __restrict__ coords,
                                              float* __restrict__ x0, int P) {
    int i = blockIdx.x * 256 + threadIdx.x;
    if (i >= P) return;
    x0[coords[2 * i] * S0 + coords[2 * i + 1]] = 0.f;
}

// ---- scatter points onto dense grid -----------------------------------------
__global__ __launch_bounds__(256) void k_scatter(const int* __restrict__ coords,
                                                 const float* __restrict__ feats,
                                                 float* __restrict__ x0,
                                                 unsigned* __restrict__ m0b, int P) {
    int i = blockIdx.x * 256 + threadIdx.x;
    if (i >= P) return;
    int r = coords[2 * i], c = coords[2 * i + 1];
    int idx = r * S0 + c;
    atomicAdd(&x0[idx], feats[i]);
    atomicOr(&m0b[idx >> 5], 1u << (idx & 31));
}

// ---- layer 1: sparse conv 5x5 1->10 + ELU + maxpool5 (mask-bitfield-driven) -
__global__ __launch_bounds__(256) void k_l1(const float* __restrict__ x0,
                                            const unsigned* __restrict__ m0b,
                                            const float* __restrict__ w1,
                                            float* __restrict__ y1,
                                            unsigned char* __restrict__ m1) {
    __shared__ float w1s[250];
    int tid = threadIdx.x;
    if (tid < 250) w1s[tid] = w1[tid];
    __syncthreads();
    int t = blockIdx.x * 256 + tid;       // grid exact: 720*720 = 518400
    int pr = t / S1, pc = t % S1;
    int r0 = pr * 5 - 2, c0 = pc * 5 - 2; // 9x9 patch origin
    unsigned rows[9];
#pragma unroll
    for (int rr = 0; rr < 9; rr++) {
        unsigned bits = 0;
        int gr = r0 + rr;
        if (gr >= 0 && gr < S0) {
            int cs = c0 < 0 ? 0 : c0;
            int ce = c0 + 8 > S0 - 1 ? S0 - 1 : c0 + 8;
            int span = ce - cs;
            size_t i0 = (size_t)gr * S0 + cs;
            unsigned sh = (unsigned)(i0 & 31);
            unsigned long long two = (unsigned long long)m0b[i0 >> 5] >> sh;
            if ((int)sh + span >= 32)
                two |= (unsigned long long)m0b[(i0 >> 5) + 1] << (32 - sh);
            bits = (unsigned)(two & ((1u << (span + 1)) - 1));
            bits <<= (cs - c0);
        }
        rows[rr] = bits;
    }
    unsigned any25 = 0;
#pragma unroll
    for (int dy = 0; dy < 5; dy++) any25 |= (rows[2 + dy] >> 2) & 0x1Fu;
    float* yo = &y1[(size_t)t * 10];
    if (!any25) {
#pragma unroll
        for (int q = 0; q < 5; q++) ((float2*)yo)[q] = make_float2(0.f, 0.f);
        m1[t] = 0;
        return;
    }
    float2 mx[5];
#pragma unroll
    for (int q = 0; q < 5; q++) mx[q] = make_float2(NEGF, NEGF);
    for (int dy = 0; dy < 5; dy++) {
        unsigned crow = (rows[2 + dy] >> 2) & 0x1Fu;
        while (crow) {
            int dx = __ffs(crow) - 1; crow &= crow - 1;
            float2 acc[5];
#pragma unroll
            for (int q = 0; q < 5; q++) acc[q] = make_float2(0.f, 0.f);
#pragma unroll
            for (int ky = 0; ky < 5; ky++) {
                unsigned nrow = (rows[dy + ky] >> dx) & 0x1Fu;
                size_t rowbase = (size_t)(r0 + dy + ky) * S0 + (c0 + dx);
                while (nrow) {
                    int kx = __ffs(nrow) - 1; nrow &= nrow - 1;
                    float xv = x0[rowbase + kx];
                    const float2* wp = (const float2*)&w1s[(ky * 5 + kx) * 10];
#pragma unroll
                    for (int q = 0; q < 5; q++) {
                        float2 w = wp[q];
                        acc[q].x = fmaf(xv, w.x, acc[q].x);
                        acc[q].y = fmaf(xv, w.y, acc[q].y);
                    }
                }
            }
#pragma unroll
            for (int q = 0; q < 5; q++) {
                mx[q].x = fmaxf(mx[q].x, acc[q].x);
                mx[q].y = fmaxf(mx[q].y, acc[q].y);
            }
        }
    }
#pragma unroll
    for (int q = 0; q < 5; q++) {
        float2 o;
        o.x = eluf(mx[q].x); o.y = eluf(mx[q].y);
        ((float2*)yo)[q] = o;
    }
    m1[t] = 1;
}

// ---- layer 2: fused conv 5x5 10->64 (cell-gated) + ELU + maxpool5 -----------
// Block = 2x2 pool sites (72x72 grid, 256 thr; wave = one site).
__global__ __launch_bounds__(256) void k_l2(const float* __restrict__ y1,
                                            const unsigned char* __restrict__ m1,
                                            const float* __restrict__ w2,
                                            float* __restrict__ y2,
                                            unsigned char* __restrict__ m2) {
    __shared__ float win[196 * 12];      // 14x14 cells x 12 (10ch + 2 pad)
    __shared__ unsigned char sm[196];
    int b = blockIdx.x;                  // 0..5183
    int bpr = b / 72, bpc = b % 72;
    int r0 = bpr * 10 - 2, c0 = bpc * 10 - 2;
    int tid = threadIdx.x;
    if (tid < 196) {
        int gr = r0 + tid / 14, gc = c0 + tid % 14;
        bool ok = (gr >= 0 && gr < S1 && gc >= 0 && gc < S1);
        sm[tid] = ok ? m1[gr * S1 + gc] : (unsigned char)0;
        float* dst = &win[tid * 12];
        if (ok) {
            const float2* src = (const float2*)&y1[((size_t)gr * S1 + gc) * 10];
#pragma unroll
            for (int q = 0; q < 5; q++) ((float2*)dst)[q] = src[q];
        } else {
#pragma unroll
            for (int q = 0; q < 5; q++) ((float2*)dst)[q] = make_float2(0.f, 0.f);
        }
        dst[10] = 0.f; dst[11] = 0.f;
    }
    __syncthreads();
    int wave = tid >> 6;                 // 0..3 -> site (sr,sc) in 2x2
    int sr = wave >> 1, sc = wave & 1;
    int c = tid & 63;                    // out channel
    int so = sr * 5 * 14 + sc * 5;       // site origin within 14x14 window
    unsigned mbits = 0;
#pragma unroll
    for (int cell = 0; cell < 25; cell++) {
        if (sm[so + (2 + cell / 5) * 14 + (2 + cell % 5)]) mbits |= (1u << cell);
    }
    mbits = (unsigned)__builtin_amdgcn_readfirstlane((int)mbits);
    float acc[25];
#pragma unroll
    for (int i = 0; i < 25; i++) acc[i] = 0.f;
    for (int t5 = 0; t5 < 25; t5++) {
        float w[10];
#pragma unroll
        for (int ci = 0; ci < 10; ci++) w[ci] = w2[(t5 * 10 + ci) * 64 + c];
        int base = so + (t5 / 5) * 14 + (t5 % 5);
#pragma unroll
        for (int cell = 0; cell < 25; cell++) {
            if (mbits & (1u << cell)) {
                const float4* xp = (const float4*)&win[(base + (cell / 5) * 14 + (cell % 5)) * 12];
                float4 xa = xp[0], xb = xp[1], xc = xp[2];
                float a = acc[cell];
                a = fmaf(xa.x, w[0], a); a = fmaf(xa.y, w[1], a);
                a = fmaf(xa.z, w[2], a); a = fmaf(xa.w, w[3], a);
                a = fmaf(xb.x, w[4], a); a = fmaf(xb.y, w[5], a);
                a = fmaf(xb.z, w[6], a); a = fmaf(xb.w, w[7], a);
                a = fmaf(xc.x, w[8], a); a = fmaf(xc.y, w[9], a);
                acc[cell] = a;
            }
        }
    }
    float mx = NEGF;
#pragma unroll
    for (int cell = 0; cell < 25; cell++)
        if (mbits & (1u << cell)) mx = fmaxf(mx, acc[cell]);
    bool any = (mbits != 0);
    int site = (bpr * 2 + sr) * S2 + bpc * 2 + sc;
    y2[(size_t)site * 64 + c] = any ? eluf(mx) : 0.f;
    if (c == 0) m2[site] = any ? 1 : 0;
}

// ---- layer 3: fused conv 5x5 64->128 + ELU + maxpool4 -> 36^2 ---------------
// (round-7/12 version, best measured: ~151 us) 256 thr; thread = (co-pair, kq).
__global__ __launch_bounds__(256) void k_l3(const float* __restrict__ y2,
                                            const unsigned char* __restrict__ m2,
                                            const float* __restrict__ w3,
                                            float* __restrict__ y3,
                                            unsigned char* __restrict__ m3) {
    __shared__ float win[8 * 8 * 64];    // 16 KB, [cell(r*8+c)][ci]
    __shared__ float part[4][16][128];   // 32 KB, [kq][cell][co]
    __shared__ unsigned char sm[16];
    int b = blockIdx.x;                  // 0..1295
    int ppr = b / S3, ppc = b % S3;
    int r0 = ppr * 4 - 2, c0 = ppc * 4 - 2;
    int tid = threadIdx.x;
    float4* win4 = (float4*)win;
    for (int k = tid; k < 1024; k += 256) {
        int cellk = k >> 4, q = k & 15;
        int gr = r0 + (cellk >> 3), gc = c0 + (cellk & 7);
        float4 v = make_float4(0.f, 0.f, 0.f, 0.f);
        if (gr >= 0 && gr < S2 && gc >= 0 && gc < S2)
            v = ((const float4*)y2)[((size_t)gr * S2 + gc) * 16 + q];
        win4[k] = v;
    }
    if (tid < 16) sm[tid] = m2[(ppr * 4 + (tid >> 2)) * S2 + ppc * 4 + (tid & 3)];
    __syncthreads();
    int cp = tid & 63;                   // co-pair -> co = cp*2, cp*2+1
    int kq = tid >> 6;                   // ci-quarter 0..3 (ci in [kq*16, kq*16+16))
    float2 acc[16];
#pragma unroll
    for (int i = 0; i < 16; i++) acc[i] = make_float2(0.f, 0.f);
#pragma unroll 1
    for (int t5 = 0; t5 < 25; t5++) {
        int ky = t5 / 5, kx = t5 % 5;
        const float* wb = &w3[(size_t)(t5 * 64 + kq * 16) * 128 + cp * 2];
        int xbase = (ky * 8 + kx) * 16 + kq * 4;   // + cell offset + j
#pragma unroll
        for (int j = 0; j < 4; j++) {
            float2 w0 = *(const float2*)&wb[(j * 4 + 0) * 128];
            float2 w1 = *(const float2*)&wb[(j * 4 + 1) * 128];
            float2 w2v = *(const float2*)&wb[(j * 4 + 2) * 128];
            float2 w3v = *(const float2*)&wb[(j * 4 + 3) * 128];
#pragma unroll
            for (int cell = 0; cell < 16; cell++) {
                float4 xv = win4[xbase + ((cell >> 2) * 8 + (cell & 3)) * 16 + j];
                float2 a = acc[cell];
                a.x = fmaf(xv.x, w0.x, a.x); a.y = fmaf(xv.x, w0.y, a.y);
                a.x = fmaf(xv.y, w1.x, a.x); a.y = fmaf(xv.y, w1.y, a.y);
                a.x = fmaf(xv.z, w2v.x, a.x); a.y = fmaf(xv.z, w2v.y, a.y);
                a.x = fmaf(xv.w, w3v.x, a.x); a.y = fmaf(xv.w, w3v.y, a.y);
                acc[cell] = a;
            }
        }
    }
#pragma unroll
    for (int cell = 0; cell < 16; cell++)
        *(float2*)&part[kq][cell][cp * 2] = acc[cell];
    __syncthreads();
    bool any = false;
#pragma unroll
    for (int i = 0; i < 16; i++) any |= (sm[i] != 0);
    if (tid < 128) {
        int co = tid;
        float m = NEGF;
#pragma unroll
        for (int cell = 0; cell < 16; cell++) {
            if (sm[cell]) {
                float v = part[0][cell][co] + part[1][cell][co]
                        + part[2][cell][co] + part[3][cell][co];
                m = fmaxf(m, v);
            }
        }
        y3[(size_t)b * 128 + co] = any ? eluf(m) : 0.f;
    }
    if (tid == 0) m3[b] = any ? 1 : 0;
}

// ---- layer 4 conv, K-split over ky: block = (pool cell, ky) -----------------
__global__ __launch_bounds__(256) void k_l4(const float* __restrict__ y3,
                                            const float* __restrict__ w4,
                                            float* __restrict__ part) {
    __shared__ float win[4 * 8 * 128];  // 16 KB
    int b = blockIdx.x;                  // 0..404
    int p = b / 5, ky = b % 5;
    int ppr = p / S4, ppc = p % S4;
    int r0 = ppr * 4 - 2 + ky, c0 = ppc * 4 - 2;
    int tid = threadIdx.x;
    float4* win4 = (float4*)win;
    for (int k = tid; k < 1024; k += 256) {
        int cellk = k >> 5, q = k & 31;  // cellk = rr*8+cc, rr 0..3
        int gr = r0 + (cellk >> 3), gc = c0 + (cellk & 7);
        float4 v = make_float4(0.f, 0.f, 0.f, 0.f);
        if (gr >= 0 && gr < S3 && gc >= 0 && gc < S3)
            v = ((const float4*)y3)[((size_t)gr * S3 + gc) * 32 + q];
        win4[k] = v;
    }
    __syncthreads();
    int cq = tid & 63, pr = tid >> 6;    // co-quad 0..63, cell-row 0..3
    int co4 = cq * 4;
    float4 acc[4];
#pragma unroll
    for (int i = 0; i < 4; i++) acc[i] = make_float4(0.f, 0.f, 0.f, 0.f);
#pragma unroll 1
    for (int kx = 0; kx < 5; kx++) {
        int rowbase = pr * 8 + kx;                           // + pc
        const float4* wq = (const float4*)&w4[(size_t)((ky * 5 + kx) * 128) * 256 + co4];
#pragma unroll 4
        for (int ci4 = 0; ci4 < 32; ci4++) {
            float4 xv0 = win4[(rowbase + 0) * 32 + ci4];
            float4 xv1 = win4[(rowbase + 1) * 32 + ci4];
            float4 xv2 = win4[(rowbase + 2) * 32 + ci4];
            float4 xv3 = win4[(rowbase + 3) * 32 + ci4];
            float4 w0 = wq[(ci4 * 4 + 0) * 64];
            float4 w1 = wq[(ci4 * 4 + 1) * 64];
            float4 w2v = wq[(ci4 * 4 + 2) * 64];
            float4 w3v = wq[(ci4 * 4 + 3) * 64];
            fma4(acc[0], xv0.x, w0); fma4(acc[0], xv0.y, w1); fma4(acc[0], xv0.z, w2v); fma4(acc[0], xv0.w, w3v);
            fma4(acc[1], xv1.x, w0); fma4(acc[1], xv1.y, w1); fma4(acc[1], xv1.z, w2v); fma4(acc[1], xv1.w, w3v);
            fma4(acc[2], xv2.x, w0); fma4(acc[2], xv2.y, w1); fma4(acc[2], xv2.z, w2v); fma4(acc[2], xv2.w, w3v);
            fma4(acc[3], xv3.x, w0); fma4(acc[3], xv3.y, w1); fma4(acc[3], xv3.z, w2v); fma4(acc[3], xv3.w, w3v);
        }
    }
#pragma unroll
    for (int pc = 0; pc < 4; pc++) {
        int cell = pr * 4 + pc;
        *(float4*)&part[(((size_t)p * 5 + ky) * 16 + cell) * 256 + co4] = acc[pc];
    }
}

// ---- layer 4 reduce K-partials + ELU + maxpool4 -> 9^2 ----------------------
__global__ __launch_bounds__(256) void k_p4(const float* __restrict__ part,
                                            const unsigned char* __restrict__ m3,
                                            float* __restrict__ y4) {
    int p = blockIdx.x;                  // 0..80
    int co = threadIdx.x;                // 0..255
    int ppr = p / S4, ppc = p % S4;
    float mx = NEGF;
    bool any = false;
    for (int cell = 0; cell < 16; cell++) {
        int site = (ppr * 4 + (cell >> 2)) * S3 + ppc * 4 + (cell & 3);
        if (!m3[site]) continue;
        any = true;
        float s = 0.f;
#pragma unroll
        for (int ky = 0; ky < 5; ky++)
            s += part[(((size_t)p * 5 + ky) * 16 + cell) * 256 + co];
        mx = fmaxf(mx, s);
    }
    y4[(size_t)p * 256 + co] = any ? eluf(mx) : 0.f;
}

// ---- fc1: 81 blocks x 256 thr; thread = one NCHW row; coalesced W rows ------
// h[j] = sum_i y4_nchw[i] * W[i][j]. Each thread loads its row's 32 weights
// (8x dwordx4, consecutive 128 B blocks across lanes -> fully coalesced),
// wave shfl-reduce, 4x32 LDS, one atomicAdd per (block, j). h1 pre-zeroed.
__global__ __launch_bounds__(256) void k_fc1(const float* __restrict__ y4,
                                             const float* __restrict__ fc1_w,
                                             float* __restrict__ h1) {
    __shared__ float wsum[4][32];
    int t = threadIdx.x;
    int i = blockIdx.x * 256 + t;        // 0..20735 (grid exact: 81*256)
    int c = i / 81, rem = i % 81;        // NCHW flatten: i = c*81 + h*9 + w
    float x = y4[(size_t)rem * 256 + c];
    const float4* wr = (const float4*)&fc1_w[(size_t)i * 32];
    float4 w[8];
#pragma unroll
    for (int q = 0; q < 8; q++) w[q] = wr[q];
    int lane = t & 63, wv = t >> 6;
#pragma unroll
    for (int q = 0; q < 8; q++) {
#pragma unroll
        for (int k = 0; k < 4; k++) {
            float v = x * ((&w[q].x)[k]);
            v += __shfl_down(v, 32, 64);
            v += __shfl_down(v, 16, 64);
            v += __shfl_down(v, 8, 64);
            v += __shfl_down(v, 4, 64);
            v += __shfl_down(v, 2, 64);
            v += __shfl_down(v, 1, 64);
            if (lane == 0) wsum[wv][q * 4 + k] = v;
        }
    }
    __syncthreads();
    if (t < 32) {
        float s = wsum[0][t] + wsum[1][t] + wsum[2][t] + wsum[3][t];
        atomicAdd(&h1[t], s);
    }
}

// ---- fc2 + softmax ----------------------------------------------------------
__global__ __launch_bounds__(64) void k_fc2(const float* __restrict__ h1,
                                            const float* __restrict__ fc1_b,
                                            const float* __restrict__ fc2_w,
                                            const float* __restrict__ fc2_b,
                                            float* __restrict__ out) {
    __shared__ float hv[32];
    __shared__ float lg[5];
    int tid = threadIdx.x;
    if (tid < 32) hv[tid] = eluf(h1[tid] + fc1_b[tid]);
    __syncthreads();
    if (tid < 5) {
        float s = fc2_b[tid];
        for (int j = 0; j < 32; j++) s = fmaf(hv[j], fc2_w[j * 5 + tid], s);
        lg[tid] = s;
    }
    __syncthreads();
    if (tid == 0) {
        float m = lg[0];
        for (int k = 1; k < 5; k++) m = fmaxf(m, lg[k]);
        float e[5], sum = 0.f;
        for (int k = 0; k < 5; k++) { e[k] = expf(lg[k] - m); sum += e[k]; }
        for (int k = 0; k < 5; k++) out[k] = e[k] / sum;
    }
}

extern "C" void kernel_launch(void* const* d_in, const int* in_sizes, int n_in,
                              void* d_out, int out_size, void* d_ws, size_t ws_size,
                              hipStream_t stream) {
    const int* coords = (const int*)d_in[0];
    const float* feats = (const float*)d_in[1];
    const float* w1 = (const float*)d_in[2];
    const float* w2 = (const float*)d_in[3];
    const float* w3 = (const float*)d_in[4];
    const float* w4 = (const float*)d_in[5];
    const float* fc1w = (const float*)d_in[6];
    const float* fc1b = (const float*)d_in[7];
    const float* fc2w = (const float*)d_in[8];
    const float* fc2b = (const float*)d_in[9];
    float* out = (float*)d_out;
    char* ws = (char*)d_ws;
    float* x0 = (float*)(ws + OFF_X0);
    unsigned* m0b = (unsigned*)(ws + OFF_M0B);
    float* y1 = (float*)(ws + OFF_Y1);
    unsigned char* m1g = (unsigned char*)(ws + OFF_M1);
    float* y2 = (float*)(ws + OFF_Y2);
    unsigned char* m2g = (unsigned char*)(ws + OFF_M2);
    float* y3 = (float*)(ws + OFF_Y3);
    unsigned char* m3g = (unsigned char*)(ws + OFF_M3);
    float* y4 = (float*)(ws + OFF_Y4);
    float* h1 = (float*)(ws + OFF_H1);
    float* p4 = (float*)(ws + OFF_P4);
    int P = in_sizes[1];

    // zero only the mask bitfield (1.62 MB); x0 zeroed sparsely by k_zero.
    hipMemsetAsync(ws + OFF_M0B, 0, 1620000, stream);
    k_zero<<<(P + 255) / 256, 256, 0, stream>>>(coords, x0, P);
    k_scatter<<<(P + 255) / 256, 256, 0, stream>>>(coords, feats, x0, m0b, P);
    k_l1<<<(S1 * S1) / 256, 256, 0, stream>>>(x0, m0b, w1, y1, m1g);
    k_l2<<<72 * 72, 256, 0, stream>>>(y1, m1g, w2, y2, m2g);
    k_l3<<<S3 * S3, 256, 0, stream>>>(y2, m2g, w3, y3, m3g);
    k_l4<<<S4 * S4 * 5, 256, 0, stream>>>(y3, w4, p4);
    k_p4<<<S4 * S4, 256, 0, stream>>>(p4, m3g, y4);
    hipMemsetAsync(ws + OFF_H1, 0, 128, stream);   // zero h1 (region is dead x0 space)
    k_fc1<<<81, 256, 0, stream>>>(y4, fc1w, h1);
    k_fc2<<<1, 64, 0, stream>>>(h1, fc1b, fc2w, fc2b, out);
}

// Round 15
// 411.441 us; speedup vs baseline: 3.0190x; 1.2057x over previous
//
#include <hip/hip_runtime.h>
#include <math.h>

#define S0 3600
#define S1 720
#define S2 144
#define S3 36
#define S4 9
#define NEGF (-1e30f)

// ---- workspace layout (bytes). Peak 74.72 MB (proven rounds 2-14).
static constexpr size_t OFF_X0  = 0;                                    // f32 [3600*3600] = 51,840,000
static constexpr size_t OFF_M0B = (size_t)S0 * S0 * 4;                  // u32 bitfield    = 1,620,000
static constexpr size_t OFF_Y1  = OFF_M0B + 1620000;                    // f32 [720*720*10] @53,460,000
static constexpr size_t OFF_M1  = OFF_Y1 + (size_t)S1 * S1 * 10 * 4;    // u8  [720*720]    @74,196,000
// aliased into dead x0 region (used from conv2 onward):
static constexpr size_t OFF_Y2  = 0;                                    // f32 [144*144*64]  = 5,308,416
static constexpr size_t OFF_M2  = OFF_Y2 + (size_t)S2 * S2 * 64 * 4;    // u8  [144*144]
static constexpr size_t OFF_Y3  = OFF_M2 + 20736;                       // f32 [36*36*128] @5,329,152
static constexpr size_t OFF_M3  = OFF_Y3 + (size_t)S3 * S3 * 128 * 4;   // u8  [36*36]     @5,992,704
static constexpr size_t OFF_Y4  = OFF_M3 + 1296;                        // f32 [9*9*256]   @5,994,000
static constexpr size_t OFF_H1  = OFF_Y4 + (size_t)S4 * S4 * 256 * 4;   // f32 [32]        @6,076,944
static constexpr size_t OFF_P4  = 6077200;                              // f32 [81*5*16*256] ends 12,712,720
// bf16 staging for MFMA l3 (dead x0 space, after p4):
static constexpr size_t OFF_Y2H = 13000000;                             // bf16 [20736*64] = 2,654,208
static constexpr size_t OFF_Y2L = 15700000;                             // bf16 [20736*64]
static constexpr size_t OFF_W3H = 18400000;                             // bf16 frags [50*8*64*8] = 409,600
static constexpr size_t OFF_W3L = 18816000;                             // bf16 frags (ends 19,225,600)

typedef __attribute__((ext_vector_type(8))) short bf16x8;
typedef __attribute__((ext_vector_type(4))) float f32x4;

__device__ __forceinline__ float eluf(float x) { return x > 0.f ? x : expm1f(x); }
__device__ __forceinline__ void fma4(float4& a, float s, const float4& w) {
    a.x = fmaf(s, w.x, a.x); a.y = fmaf(s, w.y, a.y);
    a.z = fmaf(s, w.z, a.z); a.w = fmaf(s, w.w, a.w);
}
__device__ __forceinline__ unsigned short f2bf(float f) {
    unsigned u = __float_as_uint(f);
    unsigned r = u + 0x7FFFu + ((u >> 16) & 1u);
    return (unsigned short)(r >> 16);
}
__device__ __forceinline__ float bf2f(unsigned short h) {
    return __uint_as_float((unsigned)h << 16);
}

// ---- zero x0 at the active coordinates --------------------------------------
__global__ __launch_bounds__(256) void k_zero(const int* __restrict__ coords,
                                              float* __restrict__ x0, int P) {
    int i = blockIdx.x * 256 + threadIdx.x;
    if (i >= P) return;
    x0[coords[2 * i] * S0 + coords[2 * i + 1]] = 0.f;
}

// ---- scatter points onto dense grid -----------------------------------------
__global__ __launch_bounds__(256) void k_scatter(const int* __restrict__ coords,
                                                 const float* __restrict__ feats,
                                                 float* __restrict__ x0,
                                                 unsigned* __restrict__ m0b, int P) {
    int i = blockIdx.x * 256 + threadIdx.x;
    if (i >= P) return;
    int r = coords[2 * i], c = coords[2 * i + 1];
    int idx = r * S0 + c;
    atomicAdd(&x0[idx], feats[i]);
    atomicOr(&m0b[idx >> 5], 1u << (idx & 31));
}

// ---- layer 1: sparse conv 5x5 1->10 + ELU + maxpool5 (mask-bitfield-driven) -
__global__ __launch_bounds__(256) void k_l1(const float* __restrict__ x0,
                                            const unsigned* __restrict__ m0b,
                                            const float* __restrict__ w1,
                                            float* __restrict__ y1,
                                            unsigned char* __restrict__ m1) {
    __shared__ float w1s[250];
    int tid = threadIdx.x;
    if (tid < 250) w1s[tid] = w1[tid];
    __syncthreads();
    int t = blockIdx.x * 256 + tid;       // grid exact: 720*720
    int pr = t / S1, pc = t % S1;
    int r0 = pr * 5 - 2, c0 = pc * 5 - 2;
    unsigned rows[9];
#pragma unroll
    for (int rr = 0; rr < 9; rr++) {
        unsigned bits = 0;
        int gr = r0 + rr;
        if (gr >= 0 && gr < S0) {
            int cs = c0 < 0 ? 0 : c0;
            int ce = c0 + 8 > S0 - 1 ? S0 - 1 : c0 + 8;
            int span = ce - cs;
            size_t i0 = (size_t)gr * S0 + cs;
            unsigned sh = (unsigned)(i0 & 31);
            unsigned long long two = (unsigned long long)m0b[i0 >> 5] >> sh;
            if ((int)sh + span >= 32)
                two |= (unsigned long long)m0b[(i0 >> 5) + 1] << (32 - sh);
            bits = (unsigned)(two & ((1u << (span + 1)) - 1));
            bits <<= (cs - c0);
        }
        rows[rr] = bits;
    }
    unsigned any25 = 0;
#pragma unroll
    for (int dy = 0; dy < 5; dy++) any25 |= (rows[2 + dy] >> 2) & 0x1Fu;
    float* yo = &y1[(size_t)t * 10];
    if (!any25) {
#pragma unroll
        for (int q = 0; q < 5; q++) ((float2*)yo)[q] = make_float2(0.f, 0.f);
        m1[t] = 0;
        return;
    }
    float2 mx[5];
#pragma unroll
    for (int q = 0; q < 5; q++) mx[q] = make_float2(NEGF, NEGF);
    for (int dy = 0; dy < 5; dy++) {
        unsigned crow = (rows[2 + dy] >> 2) & 0x1Fu;
        while (crow) {
            int dx = __ffs(crow) - 1; crow &= crow - 1;
            float2 acc[5];
#pragma unroll
            for (int q = 0; q < 5; q++) acc[q] = make_float2(0.f, 0.f);
#pragma unroll
            for (int ky = 0; ky < 5; ky++) {
                unsigned nrow = (rows[dy + ky] >> dx) & 0x1Fu;
                size_t rowbase = (size_t)(r0 + dy + ky) * S0 + (c0 + dx);
                while (nrow) {
                    int kx = __ffs(nrow) - 1; nrow &= nrow - 1;
                    float xv = x0[rowbase + kx];
                    const float2* wp = (const float2*)&w1s[(ky * 5 + kx) * 10];
#pragma unroll
                    for (int q = 0; q < 5; q++) {
                        float2 w = wp[q];
                        acc[q].x = fmaf(xv, w.x, acc[q].x);
                        acc[q].y = fmaf(xv, w.y, acc[q].y);
                    }
                }
            }
#pragma unroll
            for (int q = 0; q < 5; q++) {
                mx[q].x = fmaxf(mx[q].x, acc[q].x);
                mx[q].y = fmaxf(mx[q].y, acc[q].y);
            }
        }
    }
#pragma unroll
    for (int q = 0; q < 5; q++) {
        float2 o;
        o.x = eluf(mx[q].x); o.y = eluf(mx[q].y);
        ((float2*)yo)[q] = o;
    }
    m1[t] = 1;
}

// ---- layer 2: fused conv 5x5 10->64 (cell-gated) + ELU + maxpool5 -----------
__global__ __launch_bounds__(256) void k_l2(const float* __restrict__ y1,
                                            const unsigned char* __restrict__ m1,
                                            const float* __restrict__ w2,
                                            float* __restrict__ y2,
                                            unsigned char* __restrict__ m2) {
    __shared__ float win[196 * 12];
    __shared__ unsigned char sm[196];
    int b = blockIdx.x;                  // 0..5183
    int bpr = b / 72, bpc = b % 72;
    int r0 = bpr * 10 - 2, c0 = bpc * 10 - 2;
    int tid = threadIdx.x;
    if (tid < 196) {
        int gr = r0 + tid / 14, gc = c0 + tid % 14;
        bool ok = (gr >= 0 && gr < S1 && gc >= 0 && gc < S1);
        sm[tid] = ok ? m1[gr * S1 + gc] : (unsigned char)0;
        float* dst = &win[tid * 12];
        if (ok) {
            const float2* src = (const float2*)&y1[((size_t)gr * S1 + gc) * 10];
#pragma unroll
            for (int q = 0; q < 5; q++) ((float2*)dst)[q] = src[q];
        } else {
#pragma unroll
            for (int q = 0; q < 5; q++) ((float2*)dst)[q] = make_float2(0.f, 0.f);
        }
        dst[10] = 0.f; dst[11] = 0.f;
    }
    __syncthreads();
    int wave = tid >> 6;
    int sr = wave >> 1, sc = wave & 1;
    int c = tid & 63;
    int so = sr * 5 * 14 + sc * 5;
    unsigned mbits = 0;
#pragma unroll
    for (int cell = 0; cell < 25; cell++) {
        if (sm[so + (2 + cell / 5) * 14 + (2 + cell % 5)]) mbits |= (1u << cell);
    }
    mbits = (unsigned)__builtin_amdgcn_readfirstlane((int)mbits);
    float acc[25];
#pragma unroll
    for (int i = 0; i < 25; i++) acc[i] = 0.f;
    for (int t5 = 0; t5 < 25; t5++) {
        float w[10];
#pragma unroll
        for (int ci = 0; ci < 10; ci++) w[ci] = w2[(t5 * 10 + ci) * 64 + c];
        int base = so + (t5 / 5) * 14 + (t5 % 5);
#pragma unroll
        for (int cell = 0; cell < 25; cell++) {
            if (mbits & (1u << cell)) {
                const float4* xp = (const float4*)&win[(base + (cell / 5) * 14 + (cell % 5)) * 12];
                float4 xa = xp[0], xb = xp[1], xc = xp[2];
                float a = acc[cell];
                a = fmaf(xa.x, w[0], a); a = fmaf(xa.y, w[1], a);
                a = fmaf(xa.z, w[2], a); a = fmaf(xa.w, w[3], a);
                a = fmaf(xb.x, w[4], a); a = fmaf(xb.y, w[5], a);
                a = fmaf(xb.z, w[6], a); a = fmaf(xb.w, w[7], a);
                a = fmaf(xc.x, w[8], a); a = fmaf(xc.y, w[9], a);
                acc[cell] = a;
            }
        }
    }
    float mx = NEGF;
#pragma unroll
    for (int cell = 0; cell < 25; cell++)
        if (mbits & (1u << cell)) mx = fmaxf(mx, acc[cell]);
    bool any = (mbits != 0);
    int site = (bpr * 2 + sr) * S2 + bpc * 2 + sc;
    y2[(size_t)site * 64 + c] = any ? eluf(mx) : 0.f;
    if (c == 0) m2[site] = any ? 1 : 0;
}

// ---- convert y2 -> bf16 hi/lo (Markidis split) ------------------------------
__global__ __launch_bounds__(256) void k_cvt(const float* __restrict__ y2,
                                             unsigned short* __restrict__ y2h,
                                             unsigned short* __restrict__ y2l) {
    int i = blockIdx.x * 256 + threadIdx.x;   // grid exact: 20736*64 = 1,327,104
    float v = y2[i];
    unsigned short h = f2bf(v);
    y2h[i] = h;
    y2l[i] = f2bf(v - bf2f(h));
}

// ---- convert w3 -> MFMA B-fragment layout, bf16 hi/lo -----------------------
// frag[(s*8+nt)*64 + lane][j] = w3[(t5*64 + cib*32 + quad*8 + j)*128 + nt*16 + n]
// with s = t5*2+cib, quad = lane>>4, n = lane&15.
__global__ __launch_bounds__(256) void k_cvtw(const float* __restrict__ w3,
                                              unsigned short* __restrict__ w3h,
                                              unsigned short* __restrict__ w3l) {
    int t = blockIdx.x * 256 + threadIdx.x;   // 0..25599 (grid exact: 100*256)
    int s = t >> 9, rem = t & 511;
    int nt = rem >> 6, lane = rem & 63;
    int quad = lane >> 4, n = lane & 15;
    int t5 = s >> 1, cib = s & 1;
#pragma unroll
    for (int j = 0; j < 8; j++) {
        int ci = cib * 32 + quad * 8 + j;
        float v = w3[(size_t)(t5 * 64 + ci) * 128 + nt * 16 + n];
        unsigned short h = f2bf(v);
        w3h[(size_t)t * 8 + j] = h;
        w3l[(size_t)t * 8 + j] = f2bf(v - bf2f(h));
    }
}

// ---- layer 3: MFMA conv 5x5 64->128 + ELU + maxpool4 -> 36^2 ----------------
// One block per pool site, 4 waves; wave wv covers co-tiles {2wv, 2wv+1}.
// A = 16 cells x K (K = 25 taps x 64 ci, 50 steps of 32) from bf16 LDS window;
// B = pre-packed fragments from global. Split: acc += ah*bh + al*bh + ah*bl.
__global__ __launch_bounds__(256) void k_l3(const unsigned short* __restrict__ y2h,
                                            const unsigned short* __restrict__ y2l,
                                            const unsigned char* __restrict__ m2,
                                            const unsigned short* __restrict__ w3h,
                                            const unsigned short* __restrict__ w3l,
                                            float* __restrict__ y3,
                                            unsigned char* __restrict__ m3) {
    __shared__ uint4 win_h4[512];        // 8x8 cells x 64 ci bf16 = 8 KB
    __shared__ uint4 win_l4[512];        // 8 KB
    __shared__ unsigned char sm[16];
    int b = blockIdx.x;                  // 0..1295
    int ppr = b / S3, ppc = b % S3;
    int r0 = ppr * 4 - 2, c0 = ppc * 4 - 2;
    int tid = threadIdx.x;
    for (int k = tid; k < 512; k += 256) {
        int cellk = k >> 3, q = k & 7;   // cellk = wr*8+wc, q = ci-octet
        int gr = r0 + (cellk >> 3), gc = c0 + (cellk & 7);
        uint4 vh = make_uint4(0, 0, 0, 0), vl = vh;
        if (gr >= 0 && gr < S2 && gc >= 0 && gc < S2) {
            vh = ((const uint4*)y2h)[(size_t)(gr * S2 + gc) * 8 + q];
            vl = ((const uint4*)y2l)[(size_t)(gr * S2 + gc) * 8 + q];
        }
        win_h4[k] = vh;
        win_l4[k] = vl;
    }
    if (tid < 16) sm[tid] = m2[(ppr * 4 + (tid >> 2)) * S2 + ppc * 4 + (tid & 3)];
    __syncthreads();
    const bf16x8* winh8 = (const bf16x8*)win_h4;
    const bf16x8* winl8 = (const bf16x8*)win_l4;
    const bf16x8* w3h8 = (const bf16x8*)w3h;
    const bf16x8* w3l8 = (const bf16x8*)w3l;
    int wv = tid >> 6, lane = tid & 63;
    int quad = lane >> 4, n = lane & 15;
    int cellr = n >> 2, cellc = n & 3;   // A-operand m = lane&15 = pool cell
    f32x4 acc0 = {0.f, 0.f, 0.f, 0.f}, acc1 = {0.f, 0.f, 0.f, 0.f};
#pragma unroll 2
    for (int s = 0; s < 50; s++) {
        int t5 = s >> 1, cib = s & 1;
        int ky = t5 / 5, kx = t5 % 5;
        int aidx = ((cellr + ky) * 8 + (cellc + kx)) * 8 + cib * 4 + quad;
        bf16x8 ah = winh8[aidx];
        bf16x8 al = winl8[aidx];
        int bbase = (s * 8 + wv * 2) * 64 + lane;
        bf16x8 bh0 = w3h8[bbase], bl0 = w3l8[bbase];
        bf16x8 bh1 = w3h8[bbase + 64], bl1 = w3l8[bbase + 64];
        acc0 = __builtin_amdgcn_mfma_f32_16x16x32_bf16(ah, bh0, acc0, 0, 0, 0);
        acc0 = __builtin_amdgcn_mfma_f32_16x16x32_bf16(al, bh0, acc0, 0, 0, 0);
        acc0 = __builtin_amdgcn_mfma_f32_16x16x32_bf16(ah, bl0, acc0, 0, 0, 0);
        acc1 = __builtin_amdgcn_mfma_f32_16x16x32_bf16(ah, bh1, acc1, 0, 0, 0);
        acc1 = __builtin_amdgcn_mfma_f32_16x16x32_bf16(al, bh1, acc1, 0, 0, 0);
        acc1 = __builtin_amdgcn_mfma_f32_16x16x32_bf16(ah, bl1, acc1, 0, 0, 0);
    }
    // C/D layout: lane holds D[m=quad*4+r][n=lane&15]; m = pool cell.
    bool anyv = false;
#pragma unroll
    for (int i = 0; i < 16; i++) anyv |= (sm[i] != 0);
    float mv0 = NEGF, mv1 = NEGF;
#pragma unroll
    for (int r = 0; r < 4; r++) {
        int cell = quad * 4 + r;
        if (sm[cell]) {
            mv0 = fmaxf(mv0, acc0[r]);
            mv1 = fmaxf(mv1, acc1[r]);
        }
    }
    mv0 = fmaxf(mv0, __shfl_xor(mv0, 16, 64));
    mv0 = fmaxf(mv0, __shfl_xor(mv0, 32, 64));
    mv1 = fmaxf(mv1, __shfl_xor(mv1, 16, 64));
    mv1 = fmaxf(mv1, __shfl_xor(mv1, 32, 64));
    if (quad == 0) {
        int cob = wv * 32;
        y3[(size_t)b * 128 + cob + n] = anyv ? eluf(mv0) : 0.f;
        y3[(size_t)b * 128 + cob + 16 + n] = anyv ? eluf(mv1) : 0.f;
    }
    if (tid == 0) m3[b] = anyv ? 1 : 0;
}

// ---- layer 4 conv, K-split over ky: block = (pool cell, ky) -----------------
__global__ __launch_bounds__(256) void k_l4(const float* __restrict__ y3,
                                            const float* __restrict__ w4,
                                            float* __restrict__ part) {
    __shared__ float win[4 * 8 * 128];  // 16 KB
    int b = blockIdx.x;                  // 0..404
    int p = b / 5, ky = b % 5;
    int ppr = p / S4, ppc = p % S4;
    int r0 = ppr * 4 - 2 + ky, c0 = ppc * 4 - 2;
    int tid = threadIdx.x;
    float4* win4 = (float4*)win;
    for (int k = tid; k < 1024; k += 256) {
        int cellk = k >> 5, q = k & 31;
        int gr = r0 + (cellk >> 3), gc = c0 + (cellk & 7);
        float4 v = make_float4(0.f, 0.f, 0.f, 0.f);
        if (gr >= 0 && gr < S3 && gc >= 0 && gc < S3)
            v = ((const float4*)y3)[((size_t)gr * S3 + gc) * 32 + q];
        win4[k] = v;
    }
    __syncthreads();
    int cq = tid & 63, pr = tid >> 6;
    int co4 = cq * 4;
    float4 acc[4];
#pragma unroll
    for (int i = 0; i < 4; i++) acc[i] = make_float4(0.f, 0.f, 0.f, 0.f);
#pragma unroll 1
    for (int kx = 0; kx < 5; kx++) {
        int rowbase = pr * 8 + kx;
        const float4* wq = (const float4*)&w4[(size_t)((ky * 5 + kx) * 128) * 256 + co4];
#pragma unroll 4
        for (int ci4 = 0; ci4 < 32; ci4++) {
            float4 xv0 = win4[(rowbase + 0) * 32 + ci4];
            float4 xv1 = win4[(rowbase + 1) * 32 + ci4];
            float4 xv2 = win4[(rowbase + 2) * 32 + ci4];
            float4 xv3 = win4[(rowbase + 3) * 32 + ci4];
            float4 w0 = wq[(ci4 * 4 + 0) * 64];
            float4 w1 = wq[(ci4 * 4 + 1) * 64];
            float4 w2v = wq[(ci4 * 4 + 2) * 64];
            float4 w3v = wq[(ci4 * 4 + 3) * 64];
            fma4(acc[0], xv0.x, w0); fma4(acc[0], xv0.y, w1); fma4(acc[0], xv0.z, w2v); fma4(acc[0], xv0.w, w3v);
            fma4(acc[1], xv1.x, w0); fma4(acc[1], xv1.y, w1); fma4(acc[1], xv1.z, w2v); fma4(acc[1], xv1.w, w3v);
            fma4(acc[2], xv2.x, w0); fma4(acc[2], xv2.y, w1); fma4(acc[2], xv2.z, w2v); fma4(acc[2], xv2.w, w3v);
            fma4(acc[3], xv3.x, w0); fma4(acc[3], xv3.y, w1); fma4(acc[3], xv3.z, w2v); fma4(acc[3], xv3.w, w3v);
        }
    }
#pragma unroll
    for (int pc = 0; pc < 4; pc++) {
        int cell = pr * 4 + pc;
        *(float4*)&part[(((size_t)p * 5 + ky) * 16 + cell) * 256 + co4] = acc[pc];
    }
}

// ---- layer 4 reduce K-partials + ELU + maxpool4 -> 9^2 ----------------------
__global__ __launch_bounds__(256) void k_p4(const float* __restrict__ part,
                                            const unsigned char* __restrict__ m3,
                                            float* __restrict__ y4) {
    int p = blockIdx.x;
    int co = threadIdx.x;
    int ppr = p / S4, ppc = p % S4;
    float mx = NEGF;
    bool any = false;
    for (int cell = 0; cell < 16; cell++) {
        int site = (ppr * 4 + (cell >> 2)) * S3 + ppc * 4 + (cell & 3);
        if (!m3[site]) continue;
        any = true;
        float s = 0.f;
#pragma unroll
        for (int ky = 0; ky < 5; ky++)
            s += part[(((size_t)p * 5 + ky) * 16 + cell) * 256 + co];
        mx = fmaxf(mx, s);
    }
    y4[(size_t)p * 256 + co] = any ? eluf(mx) : 0.f;
}

// ---- fc1: 81 blocks x 256 thr; thread = one NCHW row; coalesced W rows ------
__global__ __launch_bounds__(256) void k_fc1(const float* __restrict__ y4,
                                             const float* __restrict__ fc1_w,
                                             float* __restrict__ h1) {
    __shared__ float wsum[4][32];
    int t = threadIdx.x;
    int i = blockIdx.x * 256 + t;
    int c = i / 81, rem = i % 81;
    float x = y4[(size_t)rem * 256 + c];
    const float4* wr = (const float4*)&fc1_w[(size_t)i * 32];
    float4 w[8];
#pragma unroll
    for (int q = 0; q < 8; q++) w[q] = wr[q];
    int lane = t & 63, wv = t >> 6;
#pragma unroll
    for (int q = 0; q < 8; q++) {
#pragma unroll
        for (int k = 0; k < 4; k++) {
            float v = x * ((&w[q].x)[k]);
            v += __shfl_down(v, 32, 64);
            v += __shfl_down(v, 16, 64);
            v += __shfl_down(v, 8, 64);
            v += __shfl_down(v, 4, 64);
            v += __shfl_down(v, 2, 64);
            v += __shfl_down(v, 1, 64);
            if (lane == 0) wsum[wv][q * 4 + k] = v;
        }
    }
    __syncthreads();
    if (t < 32) {
        float s = wsum[0][t] + wsum[1][t] + wsum[2][t] + wsum[3][t];
        atomicAdd(&h1[t], s);
    }
}

// ---- fc2 + softmax ----------------------------------------------------------
__global__ __launch_bounds__(64) void k_fc2(const float* __restrict__ h1,
                                            const float* __restrict__ fc1_b,
                                            const float* __restrict__ fc2_w,
                                            const float* __restrict__ fc2_b,
                                            float* __restrict__ out) {
    __shared__ float hv[32];
    __shared__ float lg[5];
    int tid = threadIdx.x;
    if (tid < 32) hv[tid] = eluf(h1[tid] + fc1_b[tid]);
    __syncthreads();
    if (tid < 5) {
        float s = fc2_b[tid];
        for (int j = 0; j < 32; j++) s = fmaf(hv[j], fc2_w[j * 5 + tid], s);
        lg[tid] = s;
    }
    __syncthreads();
    if (tid == 0) {
        float m = lg[0];
        for (int k = 1; k < 5; k++) m = fmaxf(m, lg[k]);
        float e[5], sum = 0.f;
        for (int k = 0; k < 5; k++) { e[k] = expf(lg[k] - m); sum += e[k]; }
        for (int k = 0; k < 5; k++) out[k] = e[k] / sum;
    }
}

extern "C" void kernel_launch(void* const* d_in, const int* in_sizes, int n_in,
                              void* d_out, int out_size, void* d_ws, size_t ws_size,
                              hipStream_t stream) {
    const int* coords = (const int*)d_in[0];
    const float* feats = (const float*)d_in[1];
    const float* w1 = (const float*)d_in[2];
    const float* w2 = (const float*)d_in[3];
    const float* w3 = (const float*)d_in[4];
    const float* w4 = (const float*)d_in[5];
    const float* fc1w = (const float*)d_in[6];
    const float* fc1b = (const float*)d_in[7];
    const float* fc2w = (const float*)d_in[8];
    const float* fc2b = (const float*)d_in[9];
    float* out = (float*)d_out;
    char* ws = (char*)d_ws;
    float* x0 = (float*)(ws + OFF_X0);
    unsigned* m0b = (unsigned*)(ws + OFF_M0B);
    float* y1 = (float*)(ws + OFF_Y1);
    unsigned char* m1g = (unsigned char*)(ws + OFF_M1);
    float* y2 = (float*)(ws + OFF_Y2);
    unsigned char* m2g = (unsigned char*)(ws + OFF_M2);
    float* y3 = (float*)(ws + OFF_Y3);
    unsigned char* m3g = (unsigned char*)(ws + OFF_M3);
    float* y4 = (float*)(ws + OFF_Y4);
    float* h1 = (float*)(ws + OFF_H1);
    float* p4 = (float*)(ws + OFF_P4);
    unsigned short* y2h = (unsigned short*)(ws + OFF_Y2H);
    unsigned short* y2l = (unsigned short*)(ws + OFF_Y2L);
    unsigned short* w3h = (unsigned short*)(ws + OFF_W3H);
    unsigned short* w3l = (unsigned short*)(ws + OFF_W3L);
    int P = in_sizes[1];

    hipMemsetAsync(ws + OFF_M0B, 0, 1620000, stream);
    k_zero<<<(P + 255) / 256, 256, 0, stream>>>(coords, x0, P);
    k_scatter<<<(P + 255) / 256, 256, 0, stream>>>(coords, feats, x0, m0b, P);
    k_cvtw<<<100, 256, 0, stream>>>(w3, w3h, w3l);
    k_l1<<<(S1 * S1) / 256, 256, 0, stream>>>(x0, m0b, w1, y1, m1g);
    k_l2<<<72 * 72, 256, 0, stream>>>(y1, m1g, w2, y2, m2g);
    k_cvt<<<(S2 * S2 * 64) / 256, 256, 0, stream>>>(y2, y2h, y2l);
    k_l3<<<S3 * S3, 256, 0, stream>>>(y2h, y2l, m2g, w3h, w3l, y3, m3g);
    k_l4<<<S4 * S4 * 5, 256, 0, stream>>>(y3, w4, p4);
    k_p4<<<S4 * S4, 256, 0, stream>>>(p4, m3g, y4);
    hipMemsetAsync(ws + OFF_H1, 0, 128, stream);
    k_fc1<<<81, 256, 0, stream>>>(y4, fc1w, h1);
    k_fc2<<<1, 64, 0, stream>>>(h1, fc1b, fc2w, fc2b, out);
}

// Round 16
// 365.206 us; speedup vs baseline: 3.4012x; 1.1266x over previous
//
#include <hip/hip_runtime.h>
#include <math.h>

#define S0 3600
#define S1 720
#define S2 144
#define S3 36
#define S4 9
#define NEGF (-1e30f)

// ---- workspace layout (bytes). Peak 74.72 MB (proven rounds 2-15).
static constexpr size_t OFF_X0  = 0;                                    // f32 [3600*3600] = 51,840,000
static constexpr size_t OFF_M0B = (size_t)S0 * S0 * 4;                  // u32 bitfield    = 1,620,000
static constexpr size_t OFF_Y1  = OFF_M0B + 1620000;                    // f32 [720*720*10] @53,460,000
static constexpr size_t OFF_M1  = OFF_Y1 + (size_t)S1 * S1 * 10 * 4;    // u8  [720*720]    @74,196,000
// aliased into dead x0 region (everything below is written only AFTER k_l1):
static constexpr size_t OFF_Y2  = 0;                                    // f32 [144*144*64]  = 5,308,416
static constexpr size_t OFF_M2  = OFF_Y2 + (size_t)S2 * S2 * 64 * 4;    // u8  [144*144]
static constexpr size_t OFF_Y3  = OFF_M2 + 20736;                       // f32 [36*36*128] @5,329,152
static constexpr size_t OFF_M3  = OFF_Y3 + (size_t)S3 * S3 * 128 * 4;   // u8  [36*36]     @5,992,704
static constexpr size_t OFF_Y4  = OFF_M3 + 1296;                        // f32 [9*9*256]   @5,994,000
static constexpr size_t OFF_H1  = OFF_Y4 + (size_t)S4 * S4 * 256 * 4;   // f32 [32]        @6,076,944
static constexpr size_t OFF_P4  = 6077200;                              // f32 [81*5*16*256] ends 12,712,720
static constexpr size_t OFF_Y2H = 13000000;                             // bf16 [20736*64] = 2,654,208
static constexpr size_t OFF_Y2L = 15700000;                             // bf16 [20736*64]
static constexpr size_t OFF_W3H = 18400000;                             // bf16 frags [50*8*64*8] = 409,600
static constexpr size_t OFF_W3L = 18816000;                             // (ends 19,225,600)
static constexpr size_t OFF_W2H = 19240000;                             // bf16 frags [13*4*64*8] = 53,248
static constexpr size_t OFF_W2L = 19300000;                             // (ends 19,353,248)

typedef __attribute__((ext_vector_type(8))) short bf16x8;
typedef __attribute__((ext_vector_type(4))) float f32x4;

__device__ __forceinline__ float eluf(float x) { return x > 0.f ? x : expm1f(x); }
__device__ __forceinline__ void fma4(float4& a, float s, const float4& w) {
    a.x = fmaf(s, w.x, a.x); a.y = fmaf(s, w.y, a.y);
    a.z = fmaf(s, w.z, a.z); a.w = fmaf(s, w.w, a.w);
}
__device__ __forceinline__ unsigned short f2bf(float f) {
    unsigned u = __float_as_uint(f);
    unsigned r = u + 0x7FFFu + ((u >> 16) & 1u);
    return (unsigned short)(r >> 16);
}
__device__ __forceinline__ float bf2f(unsigned short h) {
    return __uint_as_float((unsigned)h << 16);
}

// ---- zero x0 at the active coordinates --------------------------------------
__global__ __launch_bounds__(256) void k_zero(const int* __restrict__ coords,
                                              float* __restrict__ x0, int P) {
    int i = blockIdx.x * 256 + threadIdx.x;
    if (i >= P) return;
    x0[coords[2 * i] * S0 + coords[2 * i + 1]] = 0.f;
}

// ---- scatter points onto dense grid -----------------------------------------
__global__ __launch_bounds__(256) void k_scatter(const int* __restrict__ coords,
                                                 const float* __restrict__ feats,
                                                 float* __restrict__ x0,
                                                 unsigned* __restrict__ m0b, int P) {
    int i = blockIdx.x * 256 + threadIdx.x;
    if (i >= P) return;
    int r = coords[2 * i], c = coords[2 * i + 1];
    int idx = r * S0 + c;
    atomicAdd(&x0[idx], feats[i]);
    atomicOr(&m0b[idx >> 5], 1u << (idx & 31));
}

// ---- layer 1: sparse conv 5x5 1->10 + ELU + maxpool5 (mask-bitfield-driven) -
__global__ __launch_bounds__(256) void k_l1(const float* __restrict__ x0,
                                            const unsigned* __restrict__ m0b,
                                            const float* __restrict__ w1,
                                            float* __restrict__ y1,
                                            unsigned char* __restrict__ m1) {
    __shared__ float w1s[250];
    int tid = threadIdx.x;
    if (tid < 250) w1s[tid] = w1[tid];
    __syncthreads();
    int t = blockIdx.x * 256 + tid;       // grid exact: 720*720
    int pr = t / S1, pc = t % S1;
    int r0 = pr * 5 - 2, c0 = pc * 5 - 2;
    unsigned rows[9];
#pragma unroll
    for (int rr = 0; rr < 9; rr++) {
        unsigned bits = 0;
        int gr = r0 + rr;
        if (gr >= 0 && gr < S0) {
            int cs = c0 < 0 ? 0 : c0;
            int ce = c0 + 8 > S0 - 1 ? S0 - 1 : c0 + 8;
            int span = ce - cs;
            size_t i0 = (size_t)gr * S0 + cs;
            unsigned sh = (unsigned)(i0 & 31);
            unsigned long long two = (unsigned long long)m0b[i0 >> 5] >> sh;
            if ((int)sh + span >= 32)
                two |= (unsigned long long)m0b[(i0 >> 5) + 1] << (32 - sh);
            bits = (unsigned)(two & ((1u << (span + 1)) - 1));
            bits <<= (cs - c0);
        }
        rows[rr] = bits;
    }
    unsigned any25 = 0;
#pragma unroll
    for (int dy = 0; dy < 5; dy++) any25 |= (rows[2 + dy] >> 2) & 0x1Fu;
    float* yo = &y1[(size_t)t * 10];
    if (!any25) {
#pragma unroll
        for (int q = 0; q < 5; q++) ((float2*)yo)[q] = make_float2(0.f, 0.f);
        m1[t] = 0;
        return;
    }
    float2 mx[5];
#pragma unroll
    for (int q = 0; q < 5; q++) mx[q] = make_float2(NEGF, NEGF);
    for (int dy = 0; dy < 5; dy++) {
        unsigned crow = (rows[2 + dy] >> 2) & 0x1Fu;
        while (crow) {
            int dx = __ffs(crow) - 1; crow &= crow - 1;
            float2 acc[5];
#pragma unroll
            for (int q = 0; q < 5; q++) acc[q] = make_float2(0.f, 0.f);
#pragma unroll
            for (int ky = 0; ky < 5; ky++) {
                unsigned nrow = (rows[dy + ky] >> dx) & 0x1Fu;
                size_t rowbase = (size_t)(r0 + dy + ky) * S0 + (c0 + dx);
                while (nrow) {
                    int kx = __ffs(nrow) - 1; nrow &= nrow - 1;
                    float xv = x0[rowbase + kx];
                    const float2* wp = (const float2*)&w1s[(ky * 5 + kx) * 10];
#pragma unroll
                    for (int q = 0; q < 5; q++) {
                        float2 w = wp[q];
                        acc[q].x = fmaf(xv, w.x, acc[q].x);
                        acc[q].y = fmaf(xv, w.y, acc[q].y);
                    }
                }
            }
#pragma unroll
            for (int q = 0; q < 5; q++) {
                mx[q].x = fmaxf(mx[q].x, acc[q].x);
                mx[q].y = fmaxf(mx[q].y, acc[q].y);
            }
        }
    }
#pragma unroll
    for (int q = 0; q < 5; q++) {
        float2 o;
        o.x = eluf(mx[q].x); o.y = eluf(mx[q].y);
        ((float2*)yo)[q] = o;
    }
    m1[t] = 1;
}

// ---- convert w2 -> MFMA B-fragment layout, bf16 hi/lo -----------------------
// K = tap*16 + ci (ci padded 10->16, taps padded 25->26); step s = 2 taps.
// frag[((s*4+nt)*64 + lane)*8 + j]: tap = 2s + (quad>>1), ci = (quad&1)*8+j,
// n = nt*16 + (lane&15).
__global__ __launch_bounds__(256) void k_cvtw2(const float* __restrict__ w2,
                                               unsigned short* __restrict__ w2h,
                                               unsigned short* __restrict__ w2l) {
    int t = blockIdx.x * 256 + threadIdx.x;   // grid exact: 13*256 = 3328
    int s = t >> 8, rem = t & 255;
    int nt = rem >> 6, lane = rem & 63;
    int quad = lane >> 4, n = lane & 15;
    int tap = 2 * s + (quad >> 1);
#pragma unroll
    for (int j = 0; j < 8; j++) {
        int ci = (quad & 1) * 8 + j;
        float v = 0.f;
        if (tap < 25 && ci < 10) v = w2[(tap * 10 + ci) * 64 + nt * 16 + n];
        unsigned short h = f2bf(v);
        w2h[(size_t)t * 8 + j] = h;
        w2l[(size_t)t * 8 + j] = f2bf(v - bf2f(h));
    }
}

// ---- layer 2: MFMA conv 5x5 10->64 + ELU + maxpool5 -> 144^2 ----------------
// Block = 2x2 pool sites (72x72 grid, 256 thr; wave = one site).
// Per site: GEMM M=25 cells (2 M-tiles), N=64 (4 N-tiles), K=416 (13 steps).
// Window 14x14 staged as bf16 hi/lo padded to 240 positions (zeros beyond)
// so padded cells/taps read exact zeros. Inactive sites early-out (68%).
__global__ __launch_bounds__(256) void k_l2(const float* __restrict__ y1,
                                            const unsigned char* __restrict__ m1,
                                            const unsigned short* __restrict__ w2h,
                                            const unsigned short* __restrict__ w2l,
                                            float* __restrict__ y2,
                                            unsigned char* __restrict__ m2) {
    __shared__ unsigned short winh[240 * 16];   // 7680 B
    __shared__ unsigned short winl[240 * 16];   // 7680 B
    __shared__ unsigned char sm[196];
    int b = blockIdx.x;                  // 0..5183
    int bpr = b / 72, bpc = b % 72;
    int r0 = bpr * 10 - 2, c0 = bpc * 10 - 2;
    int tid = threadIdx.x;
    if (tid < 240) {
        unsigned uh[8] = {0, 0, 0, 0, 0, 0, 0, 0};
        unsigned ul[8] = {0, 0, 0, 0, 0, 0, 0, 0};
        if (tid < 196) {
            int gr = r0 + tid / 14, gc = c0 + tid % 14;
            bool ok = (gr >= 0 && gr < S1 && gc >= 0 && gc < S1);
            sm[tid] = ok ? m1[gr * S1 + gc] : (unsigned char)0;
            if (ok) {
                const float2* src = (const float2*)&y1[(size_t)(gr * S1 + gc) * 10];
#pragma unroll
                for (int q = 0; q < 5; q++) {
                    float2 v = src[q];
                    unsigned short h0 = f2bf(v.x), h1 = f2bf(v.y);
                    unsigned short l0 = f2bf(v.x - bf2f(h0));
                    unsigned short l1 = f2bf(v.y - bf2f(h1));
                    uh[q] = (unsigned)h0 | ((unsigned)h1 << 16);
                    ul[q] = (unsigned)l0 | ((unsigned)l1 << 16);
                }
            }
        }
        uint4* dh = (uint4*)&winh[tid * 16];
        dh[0] = make_uint4(uh[0], uh[1], uh[2], uh[3]);
        dh[1] = make_uint4(uh[4], uh[5], uh[6], uh[7]);
        uint4* dl = (uint4*)&winl[tid * 16];
        dl[0] = make_uint4(ul[0], ul[1], ul[2], ul[3]);
        dl[1] = make_uint4(ul[4], ul[5], ul[6], ul[7]);
    }
    __syncthreads();
    int site = tid >> 6;                 // wave = one pool site
    int sr = site >> 1, sc = site & 1;
    int lane = tid & 63, quad = lane >> 4, n = lane & 15;
    int so = (sr * 5) * 14 + sc * 5;
    unsigned mbits = 0;
#pragma unroll
    for (int cell = 0; cell < 25; cell++)
        if (sm[so + (2 + cell / 5) * 14 + (2 + cell % 5)]) mbits |= (1u << cell);
    mbits = (unsigned)__builtin_amdgcn_readfirstlane((int)mbits);
    int gsite = (bpr * 2 + sr) * S2 + bpc * 2 + sc;
    if (mbits == 0) {
        if (quad == 0) {
#pragma unroll
            for (int nt = 0; nt < 4; nt++)
                y2[(size_t)gsite * 64 + nt * 16 + n] = 0.f;
        }
        if (lane == 0) m2[gsite] = 0;
        return;
    }
    const bf16x8* wh8 = (const bf16x8*)w2h;
    const bf16x8* wl8 = (const bf16x8*)w2l;
    const bf16x8* xh8 = (const bf16x8*)winh;
    const bf16x8* xl8 = (const bf16x8*)winl;
    // A-frag: lane m = cell (mt*16 + n); k = quad*8+j -> tap 2s+(quad>>1), ci-octet (quad&1)
    int cell0 = n, cell1 = 16 + n;
    int p0 = (sr * 5 + cell0 / 5) * 14 + sc * 5 + cell0 % 5;
    int p1 = (sr * 5 + cell1 / 5) * 14 + sc * 5 + cell1 % 5;
    int oct = quad & 1;
    f32x4 acc[2][4];
#pragma unroll
    for (int mt = 0; mt < 2; mt++)
#pragma unroll
        for (int nt = 0; nt < 4; nt++) acc[mt][nt] = (f32x4){0.f, 0.f, 0.f, 0.f};
#pragma unroll 1
    for (int s = 0; s < 13; s++) {
        int tap = 2 * s + (quad >> 1);            // tap 25 -> zero-padded region
        int tapoff = (tap / 5) * 14 + (tap % 5);
        bf16x8 ah0 = xh8[(p0 + tapoff) * 2 + oct];
        bf16x8 al0 = xl8[(p0 + tapoff) * 2 + oct];
        bf16x8 ah1 = xh8[(p1 + tapoff) * 2 + oct];
        bf16x8 al1 = xl8[(p1 + tapoff) * 2 + oct];
#pragma unroll
        for (int nt = 0; nt < 4; nt++) {
            bf16x8 bh = wh8[(s * 4 + nt) * 64 + lane];
            bf16x8 bl = wl8[(s * 4 + nt) * 64 + lane];
            acc[0][nt] = __builtin_amdgcn_mfma_f32_16x16x32_bf16(ah0, bh, acc[0][nt], 0, 0, 0);
            acc[0][nt] = __builtin_amdgcn_mfma_f32_16x16x32_bf16(al0, bh, acc[0][nt], 0, 0, 0);
            acc[0][nt] = __builtin_amdgcn_mfma_f32_16x16x32_bf16(ah0, bl, acc[0][nt], 0, 0, 0);
            acc[1][nt] = __builtin_amdgcn_mfma_f32_16x16x32_bf16(ah1, bh, acc[1][nt], 0, 0, 0);
            acc[1][nt] = __builtin_amdgcn_mfma_f32_16x16x32_bf16(al1, bh, acc[1][nt], 0, 0, 0);
            acc[1][nt] = __builtin_amdgcn_mfma_f32_16x16x32_bf16(ah1, bl, acc[1][nt], 0, 0, 0);
        }
    }
    // C/D: lane holds D[m = quad*4+r][n = lane&15]; m = cell within M-tile.
#pragma unroll
    for (int nt = 0; nt < 4; nt++) {
        float m = NEGF;
#pragma unroll
        for (int mt = 0; mt < 2; mt++) {
#pragma unroll
            for (int r = 0; r < 4; r++) {
                int cell = mt * 16 + quad * 4 + r;
                if (cell < 25 && (mbits & (1u << cell))) m = fmaxf(m, acc[mt][nt][r]);
            }
        }
        m = fmaxf(m, __shfl_xor(m, 16, 64));
        m = fmaxf(m, __shfl_xor(m, 32, 64));
        if (quad == 0) y2[(size_t)gsite * 64 + nt * 16 + n] = eluf(m);
    }
    if (lane == 0) m2[gsite] = 1;
}

// ---- convert y2 -> bf16 hi/lo (Markidis split) ------------------------------
__global__ __launch_bounds__(256) void k_cvt(const float* __restrict__ y2,
                                             unsigned short* __restrict__ y2h,
                                             unsigned short* __restrict__ y2l) {
    int i = blockIdx.x * 256 + threadIdx.x;   // grid exact: 20736*64
    float v = y2[i];
    unsigned short h = f2bf(v);
    y2h[i] = h;
    y2l[i] = f2bf(v - bf2f(h));
}

// ---- convert w3 -> MFMA B-fragment layout, bf16 hi/lo -----------------------
__global__ __launch_bounds__(256) void k_cvtw(const float* __restrict__ w3,
                                              unsigned short* __restrict__ w3h,
                                              unsigned short* __restrict__ w3l) {
    int t = blockIdx.x * 256 + threadIdx.x;   // grid exact: 100*256
    int s = t >> 9, rem = t & 511;
    int nt = rem >> 6, lane = rem & 63;
    int quad = lane >> 4, n = lane & 15;
    int t5 = s >> 1, cib = s & 1;
#pragma unroll
    for (int j = 0; j < 8; j++) {
        int ci = cib * 32 + quad * 8 + j;
        float v = w3[(size_t)(t5 * 64 + ci) * 128 + nt * 16 + n];
        unsigned short h = f2bf(v);
        w3h[(size_t)t * 8 + j] = h;
        w3l[(size_t)t * 8 + j] = f2bf(v - bf2f(h));
    }
}

// ---- layer 3: MFMA conv 5x5 64->128 + ELU + maxpool4 -> 36^2 ----------------
__global__ __launch_bounds__(256) void k_l3(const unsigned short* __restrict__ y2h,
                                            const unsigned short* __restrict__ y2l,
                                            const unsigned char* __restrict__ m2,
                                            const unsigned short* __restrict__ w3h,
                                            const unsigned short* __restrict__ w3l,
                                            float* __restrict__ y3,
                                            unsigned char* __restrict__ m3) {
    __shared__ uint4 win_h4[512];        // 8x8 cells x 64 ci bf16 = 8 KB
    __shared__ uint4 win_l4[512];        // 8 KB
    __shared__ unsigned char sm[16];
    int b = blockIdx.x;                  // 0..1295
    int ppr = b / S3, ppc = b % S3;
    int r0 = ppr * 4 - 2, c0 = ppc * 4 - 2;
    int tid = threadIdx.x;
    for (int k = tid; k < 512; k += 256) {
        int cellk = k >> 3, q = k & 7;
        int gr = r0 + (cellk >> 3), gc = c0 + (cellk & 7);
        uint4 vh = make_uint4(0, 0, 0, 0), vl = vh;
        if (gr >= 0 && gr < S2 && gc >= 0 && gc < S2) {
            vh = ((const uint4*)y2h)[(size_t)(gr * S2 + gc) * 8 + q];
            vl = ((const uint4*)y2l)[(size_t)(gr * S2 + gc) * 8 + q];
        }
        win_h4[k] = vh;
        win_l4[k] = vl;
    }
    if (tid < 16) sm[tid] = m2[(ppr * 4 + (tid >> 2)) * S2 + ppc * 4 + (tid & 3)];
    __syncthreads();
    const bf16x8* winh8 = (const bf16x8*)win_h4;
    const bf16x8* winl8 = (const bf16x8*)win_l4;
    const bf16x8* w3h8 = (const bf16x8*)w3h;
    const bf16x8* w3l8 = (const bf16x8*)w3l;
    int wv = tid >> 6, lane = tid & 63;
    int quad = lane >> 4, n = lane & 15;
    int cellr = n >> 2, cellc = n & 3;
    f32x4 acc0 = {0.f, 0.f, 0.f, 0.f}, acc1 = {0.f, 0.f, 0.f, 0.f};
#pragma unroll 2
    for (int s = 0; s < 50; s++) {
        int t5 = s >> 1, cib = s & 1;
        int ky = t5 / 5, kx = t5 % 5;
        int aidx = ((cellr + ky) * 8 + (cellc + kx)) * 8 + cib * 4 + quad;
        bf16x8 ah = winh8[aidx];
        bf16x8 al = winl8[aidx];
        int bbase = (s * 8 + wv * 2) * 64 + lane;
        bf16x8 bh0 = w3h8[bbase], bl0 = w3l8[bbase];
        bf16x8 bh1 = w3h8[bbase + 64], bl1 = w3l8[bbase + 64];
        acc0 = __builtin_amdgcn_mfma_f32_16x16x32_bf16(ah, bh0, acc0, 0, 0, 0);
        acc0 = __builtin_amdgcn_mfma_f32_16x16x32_bf16(al, bh0, acc0, 0, 0, 0);
        acc0 = __builtin_amdgcn_mfma_f32_16x16x32_bf16(ah, bl0, acc0, 0, 0, 0);
        acc1 = __builtin_amdgcn_mfma_f32_16x16x32_bf16(ah, bh1, acc1, 0, 0, 0);
        acc1 = __builtin_amdgcn_mfma_f32_16x16x32_bf16(al, bh1, acc1, 0, 0, 0);
        acc1 = __builtin_amdgcn_mfma_f32_16x16x32_bf16(ah, bl1, acc1, 0, 0, 0);
    }
    bool anyv = false;
#pragma unroll
    for (int i = 0; i < 16; i++) anyv |= (sm[i] != 0);
    float mv0 = NEGF, mv1 = NEGF;
#pragma unroll
    for (int r = 0; r < 4; r++) {
        int cell = quad * 4 + r;
        if (sm[cell]) {
            mv0 = fmaxf(mv0, acc0[r]);
            mv1 = fmaxf(mv1, acc1[r]);
        }
    }
    mv0 = fmaxf(mv0, __shfl_xor(mv0, 16, 64));
    mv0 = fmaxf(mv0, __shfl_xor(mv0, 32, 64));
    mv1 = fmaxf(mv1, __shfl_xor(mv1, 16, 64));
    mv1 = fmaxf(mv1, __shfl_xor(mv1, 32, 64));
    if (quad == 0) {
        int cob = wv * 32;
        y3[(size_t)b * 128 + cob + n] = anyv ? eluf(mv0) : 0.f;
        y3[(size_t)b * 128 + cob + 16 + n] = anyv ? eluf(mv1) : 0.f;
    }
    if (tid == 0) m3[b] = anyv ? 1 : 0;
}

// ---- layer 4 conv, K-split over ky: block = (pool cell, ky) -----------------
__global__ __launch_bounds__(256) void k_l4(const float* __restrict__ y3,
                                            const float* __restrict__ w4,
                                            float* __restrict__ part) {
    __shared__ float win[4 * 8 * 128];  // 16 KB
    int b = blockIdx.x;                  // 0..404
    int p = b / 5, ky = b % 5;
    int ppr = p / S4, ppc = p % S4;
    int r0 = ppr * 4 - 2 + ky, c0 = ppc * 4 - 2;
    int tid = threadIdx.x;
    float4* win4 = (float4*)win;
    for (int k = tid; k < 1024; k += 256) {
        int cellk = k >> 5, q = k & 31;
        int gr = r0 + (cellk >> 3), gc = c0 + (cellk & 7);
        float4 v = make_float4(0.f, 0.f, 0.f, 0.f);
        if (gr >= 0 && gr < S3 && gc >= 0 && gc < S3)
            v = ((const float4*)y3)[((size_t)gr * S3 + gc) * 32 + q];
        win4[k] = v;
    }
    __syncthreads();
    int cq = tid & 63, pr = tid >> 6;
    int co4 = cq * 4;
    float4 acc[4];
#pragma unroll
    for (int i = 0; i < 4; i++) acc[i] = make_float4(0.f, 0.f, 0.f, 0.f);
#pragma unroll 1
    for (int kx = 0; kx < 5; kx++) {
        int rowbase = pr * 8 + kx;
        const float4* wq = (const float4*)&w4[(size_t)((ky * 5 + kx) * 128) * 256 + co4];
#pragma unroll 4
        for (int ci4 = 0; ci4 < 32; ci4++) {
            float4 xv0 = win4[(rowbase + 0) * 32 + ci4];
            float4 xv1 = win4[(rowbase + 1) * 32 + ci4];
            float4 xv2 = win4[(rowbase + 2) * 32 + ci4];
            float4 xv3 = win4[(rowbase + 3) * 32 + ci4];
            float4 w0 = wq[(ci4 * 4 + 0) * 64];
            float4 w1 = wq[(ci4 * 4 + 1) * 64];
            float4 w2v = wq[(ci4 * 4 + 2) * 64];
            float4 w3v = wq[(ci4 * 4 + 3) * 64];
            fma4(acc[0], xv0.x, w0); fma4(acc[0], xv0.y, w1); fma4(acc[0], xv0.z, w2v); fma4(acc[0], xv0.w, w3v);
            fma4(acc[1], xv1.x, w0); fma4(acc[1], xv1.y, w1); fma4(acc[1], xv1.z, w2v); fma4(acc[1], xv1.w, w3v);
            fma4(acc[2], xv2.x, w0); fma4(acc[2], xv2.y, w1); fma4(acc[2], xv2.z, w2v); fma4(acc[2], xv2.w, w3v);
            fma4(acc[3], xv3.x, w0); fma4(acc[3], xv3.y, w1); fma4(acc[3], xv3.z, w2v); fma4(acc[3], xv3.w, w3v);
        }
    }
#pragma unroll
    for (int pc = 0; pc < 4; pc++) {
        int cell = pr * 4 + pc;
        *(float4*)&part[(((size_t)p * 5 + ky) * 16 + cell) * 256 + co4] = acc[pc];
    }
}

// ---- layer 4 reduce K-partials + ELU + maxpool4 -> 9^2 ----------------------
__global__ __launch_bounds__(256) void k_p4(const float* __restrict__ part,
                                            const unsigned char* __restrict__ m3,
                                            float* __restrict__ y4) {
    int p = blockIdx.x;
    int co = threadIdx.x;
    int ppr = p / S4, ppc = p % S4;
    float mx = NEGF;
    bool any = false;
    for (int cell = 0; cell < 16; cell++) {
        int site = (ppr * 4 + (cell >> 2)) * S3 + ppc * 4 + (cell & 3);
        if (!m3[site]) continue;
        any = true;
        float s = 0.f;
#pragma unroll
        for (int ky = 0; ky < 5; ky++)
            s += part[(((size_t)p * 5 + ky) * 16 + cell) * 256 + co];
        mx = fmaxf(mx, s);
    }
    y4[(size_t)p * 256 + co] = any ? eluf(mx) : 0.f;
}

// ---- fc1: 81 blocks x 256 thr; thread = one NCHW row; coalesced W rows ------
__global__ __launch_bounds__(256) void k_fc1(const float* __restrict__ y4,
                                             const float* __restrict__ fc1_w,
                                             float* __restrict__ h1) {
    __shared__ float wsum[4][32];
    int t = threadIdx.x;
    int i = blockIdx.x * 256 + t;
    int c = i / 81, rem = i % 81;
    float x = y4[(size_t)rem * 256 + c];
    const float4* wr = (const float4*)&fc1_w[(size_t)i * 32];
    float4 w[8];
#pragma unroll
    for (int q = 0; q < 8; q++) w[q] = wr[q];
    int lane = t & 63, wv = t >> 6;
#pragma unroll
    for (int q = 0; q < 8; q++) {
#pragma unroll
        for (int k = 0; k < 4; k++) {
            float v = x * ((&w[q].x)[k]);
            v += __shfl_down(v, 32, 64);
            v += __shfl_down(v, 16, 64);
            v += __shfl_down(v, 8, 64);
            v += __shfl_down(v, 4, 64);
            v += __shfl_down(v, 2, 64);
            v += __shfl_down(v, 1, 64);
            if (lane == 0) wsum[wv][q * 4 + k] = v;
        }
    }
    __syncthreads();
    if (t < 32) {
        float s = wsum[0][t] + wsum[1][t] + wsum[2][t] + wsum[3][t];
        atomicAdd(&h1[t], s);
    }
}

// ---- fc2 + softmax ----------------------------------------------------------
__global__ __launch_bounds__(64) void k_fc2(const float* __restrict__ h1,
                                            const float* __restrict__ fc1_b,
                                            const float* __restrict__ fc2_w,
                                            const float* __restrict__ fc2_b,
                                            float* __restrict__ out) {
    __shared__ float hv[32];
    __shared__ float lg[5];
    int tid = threadIdx.x;
    if (tid < 32) hv[tid] = eluf(h1[tid] + fc1_b[tid]);
    __syncthreads();
    if (tid < 5) {
        float s = fc2_b[tid];
        for (int j = 0; j < 32; j++) s = fmaf(hv[j], fc2_w[j * 5 + tid], s);
        lg[tid] = s;
    }
    __syncthreads();
    if (tid == 0) {
        float m = lg[0];
        for (int k = 1; k < 5; k++) m = fmaxf(m, lg[k]);
        float e[5], sum = 0.f;
        for (int k = 0; k < 5; k++) { e[k] = expf(lg[k] - m); sum += e[k]; }
        for (int k = 0; k < 5; k++) out[k] = e[k] / sum;
    }
}

extern "C" void kernel_launch(void* const* d_in, const int* in_sizes, int n_in,
                              void* d_out, int out_size, void* d_ws, size_t ws_size,
                              hipStream_t stream) {
    const int* coords = (const int*)d_in[0];
    const float* feats = (const float*)d_in[1];
    const float* w1 = (const float*)d_in[2];
    const float* w2 = (const float*)d_in[3];
    const float* w3 = (const float*)d_in[4];
    const float* w4 = (const float*)d_in[5];
    const float* fc1w = (const float*)d_in[6];
    const float* fc1b = (const float*)d_in[7];
    const float* fc2w = (const float*)d_in[8];
    const float* fc2b = (const float*)d_in[9];
    float* out = (float*)d_out;
    char* ws = (char*)d_ws;
    float* x0 = (float*)(ws + OFF_X0);
    unsigned* m0b = (unsigned*)(ws + OFF_M0B);
    float* y1 = (float*)(ws + OFF_Y1);
    unsigned char* m1g = (unsigned char*)(ws + OFF_M1);
    float* y2 = (float*)(ws + OFF_Y2);
    unsigned char* m2g = (unsigned char*)(ws + OFF_M2);
    float* y3 = (float*)(ws + OFF_Y3);
    unsigned char* m3g = (unsigned char*)(ws + OFF_M3);
    float* y4 = (float*)(ws + OFF_Y4);
    float* h1 = (float*)(ws + OFF_H1);
    float* p4 = (float*)(ws + OFF_P4);
    unsigned short* y2h = (unsigned short*)(ws + OFF_Y2H);
    unsigned short* y2l = (unsigned short*)(ws + OFF_Y2L);
    unsigned short* w3h = (unsigned short*)(ws + OFF_W3H);
    unsigned short* w3l = (unsigned short*)(ws + OFF_W3L);
    unsigned short* w2h = (unsigned short*)(ws + OFF_W2H);
    unsigned short* w2l = (unsigned short*)(ws + OFF_W2L);
    int P = in_sizes[1];

    hipMemsetAsync(ws + OFF_M0B, 0, 1620000, stream);
    k_zero<<<(P + 255) / 256, 256, 0, stream>>>(coords, x0, P);
    k_scatter<<<(P + 255) / 256, 256, 0, stream>>>(coords, feats, x0, m0b, P);
    k_l1<<<(S1 * S1) / 256, 256, 0, stream>>>(x0, m0b, w1, y1, m1g);
    // converters write into the dead-x0 region: MUST run after k_l1 (fixes
    // the R15 hazard where k_cvtw corrupted live x0 rows 1277-1335).
    k_cvtw2<<<13, 256, 0, stream>>>(w2, w2h, w2l);
    k_cvtw<<<100, 256, 0, stream>>>(w3, w3h, w3l);
    k_l2<<<72 * 72, 256, 0, stream>>>(y1, m1g, w2h, w2l, y2, m2g);
    k_cvt<<<(S2 * S2 * 64) / 256, 256, 0, stream>>>(y2, y2h, y2l);
    k_l3<<<S3 * S3, 256, 0, stream>>>(y2h, y2l, m2g, w3h, w3l, y3, m3g);
    k_l4<<<S4 * S4 * 5, 256, 0, stream>>>(y3, w4, p4);
    k_p4<<<S4 * S4, 256, 0, stream>>>(p4, m3g, y4);
    hipMemsetAsync(ws + OFF_H1, 0, 128, stream);
    k_fc1<<<81, 256, 0, stream>>>(y4, fc1w, h1);
    k_fc2<<<1, 64, 0, stream>>>(h1, fc1b, fc2w, fc2b, out);
}

// Round 17
// 364.229 us; speedup vs baseline: 3.4103x; 1.0027x over previous
//
#include <hip/hip_runtime.h>
#include <math.h>

#define S0 3600
#define S1 720
#define S2 144
#define S3 36
#define S4 9
#define NEGF (-1e30f)

// ---- workspace layout (bytes). Peak 74.72 MB (proven rounds 2-16).
static constexpr size_t OFF_X0  = 0;                                    // f32 [3600*3600] = 51,840,000
static constexpr size_t OFF_M0B = (size_t)S0 * S0 * 4;                  // u32 bitfield    = 1,620,000
static constexpr size_t OFF_Y1  = OFF_M0B + 1620000;                    // f32 [720*720*10] @53,460,000
static constexpr size_t OFF_M1  = OFF_Y1 + (size_t)S1 * S1 * 10 * 4;    // u8  [720*720]    @74,196,000
// aliased into dead x0 region (everything below written only AFTER k_l1):
static constexpr size_t OFF_Y2  = 0;                                    // f32 [144*144*64]  = 5,308,416
static constexpr size_t OFF_M2  = OFF_Y2 + (size_t)S2 * S2 * 64 * 4;    // u8  [144*144]
static constexpr size_t OFF_Y3  = OFF_M2 + 20736;                       // f32 [36*36*128] @5,329,152
static constexpr size_t OFF_M3  = OFF_Y3 + (size_t)S3 * S3 * 128 * 4;   // u8  [36*36]     @5,992,704
static constexpr size_t OFF_Y4  = OFF_M3 + 1296;                        // f32 [9*9*256]   @5,994,000
static constexpr size_t OFF_H1  = OFF_Y4 + (size_t)S4 * S4 * 256 * 4;   // f32 [32]        @6,076,944
static constexpr size_t OFF_Y2H = 13000000;                             // bf16 [20736*64] = 2,654,208
static constexpr size_t OFF_Y2L = 15700000;                             // bf16 [20736*64]
static constexpr size_t OFF_W3H = 18400000;                             // bf16 frags [50*8*64*8] = 409,600
static constexpr size_t OFF_W3L = 18816000;                             // (ends 19,225,600)
static constexpr size_t OFF_W2H = 19240000;                             // bf16 frags [13*4*64*8] = 53,248
static constexpr size_t OFF_W2L = 19300000;                             // (ends 19,353,248)
static constexpr size_t OFF_W4H = 19400000;                             // bf16 frags [100*16*64*8] = 1,638,400
static constexpr size_t OFF_W4L = 21100000;                             // (ends 22,738,400 < 51.8 MB)

typedef __attribute__((ext_vector_type(8))) short bf16x8;
typedef __attribute__((ext_vector_type(4))) float f32x4;

__device__ __forceinline__ float eluf(float x) { return x > 0.f ? x : expm1f(x); }
__device__ __forceinline__ unsigned short f2bf(float f) {
    unsigned u = __float_as_uint(f);
    unsigned r = u + 0x7FFFu + ((u >> 16) & 1u);
    return (unsigned short)(r >> 16);
}
__device__ __forceinline__ float bf2f(unsigned short h) {
    return __uint_as_float((unsigned)h << 16);
}

// ---- zero x0 at the active coordinates --------------------------------------
__global__ __launch_bounds__(256) void k_zero(const int* __restrict__ coords,
                                              float* __restrict__ x0, int P) {
    int i = blockIdx.x * 256 + threadIdx.x;
    if (i >= P) return;
    x0[coords[2 * i] * S0 + coords[2 * i + 1]] = 0.f;
}

// ---- scatter points onto dense grid -----------------------------------------
__global__ __launch_bounds__(256) void k_scatter(const int* __restrict__ coords,
                                                 const float* __restrict__ feats,
                                                 float* __restrict__ x0,
                                                 unsigned* __restrict__ m0b, int P) {
    int i = blockIdx.x * 256 + threadIdx.x;
    if (i >= P) return;
    int r = coords[2 * i], c = coords[2 * i + 1];
    int idx = r * S0 + c;
    atomicAdd(&x0[idx], feats[i]);
    atomicOr(&m0b[idx >> 5], 1u << (idx & 31));
}

// ---- layer 1: sparse conv 5x5 1->10 + ELU + maxpool5 (mask-bitfield-driven) -
__global__ __launch_bounds__(256) void k_l1(const float* __restrict__ x0,
                                            const unsigned* __restrict__ m0b,
                                            const float* __restrict__ w1,
                                            float* __restrict__ y1,
                                            unsigned char* __restrict__ m1) {
    __shared__ float w1s[250];
    int tid = threadIdx.x;
    if (tid < 250) w1s[tid] = w1[tid];
    __syncthreads();
    int t = blockIdx.x * 256 + tid;       // grid exact: 720*720
    int pr = t / S1, pc = t % S1;
    int r0 = pr * 5 - 2, c0 = pc * 5 - 2;
    unsigned rows[9];
#pragma unroll
    for (int rr = 0; rr < 9; rr++) {
        unsigned bits = 0;
        int gr = r0 + rr;
        if (gr >= 0 && gr < S0) {
            int cs = c0 < 0 ? 0 : c0;
            int ce = c0 + 8 > S0 - 1 ? S0 - 1 : c0 + 8;
            int span = ce - cs;
            size_t i0 = (size_t)gr * S0 + cs;
            unsigned sh = (unsigned)(i0 & 31);
            unsigned long long two = (unsigned long long)m0b[i0 >> 5] >> sh;
            if ((int)sh + span >= 32)
                two |= (unsigned long long)m0b[(i0 >> 5) + 1] << (32 - sh);
            bits = (unsigned)(two & ((1u << (span + 1)) - 1));
            bits <<= (cs - c0);
        }
        rows[rr] = bits;
    }
    unsigned any25 = 0;
#pragma unroll
    for (int dy = 0; dy < 5; dy++) any25 |= (rows[2 + dy] >> 2) & 0x1Fu;
    float* yo = &y1[(size_t)t * 10];
    if (!any25) {
#pragma unroll
        for (int q = 0; q < 5; q++) ((float2*)yo)[q] = make_float2(0.f, 0.f);
        m1[t] = 0;
        return;
    }
    float2 mx[5];
#pragma unroll
    for (int q = 0; q < 5; q++) mx[q] = make_float2(NEGF, NEGF);
    for (int dy = 0; dy < 5; dy++) {
        unsigned crow = (rows[2 + dy] >> 2) & 0x1Fu;
        while (crow) {
            int dx = __ffs(crow) - 1; crow &= crow - 1;
            float2 acc[5];
#pragma unroll
            for (int q = 0; q < 5; q++) acc[q] = make_float2(0.f, 0.f);
#pragma unroll
            for (int ky = 0; ky < 5; ky++) {
                unsigned nrow = (rows[dy + ky] >> dx) & 0x1Fu;
                size_t rowbase = (size_t)(r0 + dy + ky) * S0 + (c0 + dx);
                while (nrow) {
                    int kx = __ffs(nrow) - 1; nrow &= nrow - 1;
                    float xv = x0[rowbase + kx];
                    const float2* wp = (const float2*)&w1s[(ky * 5 + kx) * 10];
#pragma unroll
                    for (int q = 0; q < 5; q++) {
                        float2 w = wp[q];
                        acc[q].x = fmaf(xv, w.x, acc[q].x);
                        acc[q].y = fmaf(xv, w.y, acc[q].y);
                    }
                }
            }
#pragma unroll
            for (int q = 0; q < 5; q++) {
                mx[q].x = fmaxf(mx[q].x, acc[q].x);
                mx[q].y = fmaxf(mx[q].y, acc[q].y);
            }
        }
    }
#pragma unroll
    for (int q = 0; q < 5; q++) {
        float2 o;
        o.x = eluf(mx[q].x); o.y = eluf(mx[q].y);
        ((float2*)yo)[q] = o;
    }
    m1[t] = 1;
}

// ---- convert w2 -> MFMA B-fragment layout, bf16 hi/lo -----------------------
__global__ __launch_bounds__(256) void k_cvtw2(const float* __restrict__ w2,
                                               unsigned short* __restrict__ w2h,
                                               unsigned short* __restrict__ w2l) {
    int t = blockIdx.x * 256 + threadIdx.x;   // grid exact: 13*256
    int s = t >> 8, rem = t & 255;
    int nt = rem >> 6, lane = rem & 63;
    int quad = lane >> 4, n = lane & 15;
    int tap = 2 * s + (quad >> 1);
#pragma unroll
    for (int j = 0; j < 8; j++) {
        int ci = (quad & 1) * 8 + j;
        float v = 0.f;
        if (tap < 25 && ci < 10) v = w2[(tap * 10 + ci) * 64 + nt * 16 + n];
        unsigned short h = f2bf(v);
        w2h[(size_t)t * 8 + j] = h;
        w2l[(size_t)t * 8 + j] = f2bf(v - bf2f(h));
    }
}

// ---- layer 2: MFMA conv 5x5 10->64 + ELU + maxpool5 -> 144^2 ----------------
__global__ __launch_bounds__(256) void k_l2(const float* __restrict__ y1,
                                            const unsigned char* __restrict__ m1,
                                            const unsigned short* __restrict__ w2h,
                                            const unsigned short* __restrict__ w2l,
                                            float* __restrict__ y2,
                                            unsigned char* __restrict__ m2) {
    __shared__ unsigned short winh[240 * 16];
    __shared__ unsigned short winl[240 * 16];
    __shared__ unsigned char sm[196];
    int b = blockIdx.x;                  // 0..5183
    int bpr = b / 72, bpc = b % 72;
    int r0 = bpr * 10 - 2, c0 = bpc * 10 - 2;
    int tid = threadIdx.x;
    if (tid < 240) {
        unsigned uh[8] = {0, 0, 0, 0, 0, 0, 0, 0};
        unsigned ul[8] = {0, 0, 0, 0, 0, 0, 0, 0};
        if (tid < 196) {
            int gr = r0 + tid / 14, gc = c0 + tid % 14;
            bool ok = (gr >= 0 && gr < S1 && gc >= 0 && gc < S1);
            sm[tid] = ok ? m1[gr * S1 + gc] : (unsigned char)0;
            if (ok) {
                const float2* src = (const float2*)&y1[(size_t)(gr * S1 + gc) * 10];
#pragma unroll
                for (int q = 0; q < 5; q++) {
                    float2 v = src[q];
                    unsigned short h0 = f2bf(v.x), h1 = f2bf(v.y);
                    unsigned short l0 = f2bf(v.x - bf2f(h0));
                    unsigned short l1 = f2bf(v.y - bf2f(h1));
                    uh[q] = (unsigned)h0 | ((unsigned)h1 << 16);
                    ul[q] = (unsigned)l0 | ((unsigned)l1 << 16);
                }
            }
        }
        uint4* dh = (uint4*)&winh[tid * 16];
        dh[0] = make_uint4(uh[0], uh[1], uh[2], uh[3]);
        dh[1] = make_uint4(uh[4], uh[5], uh[6], uh[7]);
        uint4* dl = (uint4*)&winl[tid * 16];
        dl[0] = make_uint4(ul[0], ul[1], ul[2], ul[3]);
        dl[1] = make_uint4(ul[4], ul[5], ul[6], ul[7]);
    }
    __syncthreads();
    int site = tid >> 6;
    int sr = site >> 1, sc = site & 1;
    int lane = tid & 63, quad = lane >> 4, n = lane & 15;
    int so = (sr * 5) * 14 + sc * 5;
    unsigned mbits = 0;
#pragma unroll
    for (int cell = 0; cell < 25; cell++)
        if (sm[so + (2 + cell / 5) * 14 + (2 + cell % 5)]) mbits |= (1u << cell);
    mbits = (unsigned)__builtin_amdgcn_readfirstlane((int)mbits);
    int gsite = (bpr * 2 + sr) * S2 + bpc * 2 + sc;
    if (mbits == 0) {
        if (quad == 0) {
#pragma unroll
            for (int nt = 0; nt < 4; nt++)
                y2[(size_t)gsite * 64 + nt * 16 + n] = 0.f;
        }
        if (lane == 0) m2[gsite] = 0;
        return;
    }
    const bf16x8* wh8 = (const bf16x8*)w2h;
    const bf16x8* wl8 = (const bf16x8*)w2l;
    const bf16x8* xh8 = (const bf16x8*)winh;
    const bf16x8* xl8 = (const bf16x8*)winl;
    int cell0 = n, cell1 = 16 + n;
    int p0 = (sr * 5 + cell0 / 5) * 14 + sc * 5 + cell0 % 5;
    int p1 = (sr * 5 + cell1 / 5) * 14 + sc * 5 + cell1 % 5;
    int oct = quad & 1;
    f32x4 acc[2][4];
#pragma unroll
    for (int mt = 0; mt < 2; mt++)
#pragma unroll
        for (int nt = 0; nt < 4; nt++) acc[mt][nt] = (f32x4){0.f, 0.f, 0.f, 0.f};
#pragma unroll 1
    for (int s = 0; s < 13; s++) {
        int tap = 2 * s + (quad >> 1);
        int tapoff = (tap / 5) * 14 + (tap % 5);
        bf16x8 ah0 = xh8[(p0 + tapoff) * 2 + oct];
        bf16x8 al0 = xl8[(p0 + tapoff) * 2 + oct];
        bf16x8 ah1 = xh8[(p1 + tapoff) * 2 + oct];
        bf16x8 al1 = xl8[(p1 + tapoff) * 2 + oct];
#pragma unroll
        for (int nt = 0; nt < 4; nt++) {
            bf16x8 bh = wh8[(s * 4 + nt) * 64 + lane];
            bf16x8 bl = wl8[(s * 4 + nt) * 64 + lane];
            acc[0][nt] = __builtin_amdgcn_mfma_f32_16x16x32_bf16(ah0, bh, acc[0][nt], 0, 0, 0);
            acc[0][nt] = __builtin_amdgcn_mfma_f32_16x16x32_bf16(al0, bh, acc[0][nt], 0, 0, 0);
            acc[0][nt] = __builtin_amdgcn_mfma_f32_16x16x32_bf16(ah0, bl, acc[0][nt], 0, 0, 0);
            acc[1][nt] = __builtin_amdgcn_mfma_f32_16x16x32_bf16(ah1, bh, acc[1][nt], 0, 0, 0);
            acc[1][nt] = __builtin_amdgcn_mfma_f32_16x16x32_bf16(al1, bh, acc[1][nt], 0, 0, 0);
            acc[1][nt] = __builtin_amdgcn_mfma_f32_16x16x32_bf16(ah1, bl, acc[1][nt], 0, 0, 0);
        }
    }
#pragma unroll
    for (int nt = 0; nt < 4; nt++) {
        float m = NEGF;
#pragma unroll
        for (int mt = 0; mt < 2; mt++) {
#pragma unroll
            for (int r = 0; r < 4; r++) {
                int cell = mt * 16 + quad * 4 + r;
                if (cell < 25 && (mbits & (1u << cell))) m = fmaxf(m, acc[mt][nt][r]);
            }
        }
        m = fmaxf(m, __shfl_xor(m, 16, 64));
        m = fmaxf(m, __shfl_xor(m, 32, 64));
        if (quad == 0) y2[(size_t)gsite * 64 + nt * 16 + n] = eluf(m);
    }
    if (lane == 0) m2[gsite] = 1;
}

// ---- convert y2 -> bf16 hi/lo -----------------------------------------------
__global__ __launch_bounds__(256) void k_cvt(const float* __restrict__ y2,
                                             unsigned short* __restrict__ y2h,
                                             unsigned short* __restrict__ y2l) {
    int i = blockIdx.x * 256 + threadIdx.x;
    float v = y2[i];
    unsigned short h = f2bf(v);
    y2h[i] = h;
    y2l[i] = f2bf(v - bf2f(h));
}

// ---- convert w3 -> MFMA B-fragment layout, bf16 hi/lo -----------------------
__global__ __launch_bounds__(256) void k_cvtw(const float* __restrict__ w3,
                                              unsigned short* __restrict__ w3h,
                                              unsigned short* __restrict__ w3l) {
    int t = blockIdx.x * 256 + threadIdx.x;   // grid exact: 100*256
    int s = t >> 9, rem = t & 511;
    int nt = rem >> 6, lane = rem & 63;
    int quad = lane >> 4, n = lane & 15;
    int t5 = s >> 1, cib = s & 1;
#pragma unroll
    for (int j = 0; j < 8; j++) {
        int ci = cib * 32 + quad * 8 + j;
        float v = w3[(size_t)(t5 * 64 + ci) * 128 + nt * 16 + n];
        unsigned short h = f2bf(v);
        w3h[(size_t)t * 8 + j] = h;
        w3l[(size_t)t * 8 + j] = f2bf(v - bf2f(h));
    }
}

// ---- convert w4 -> MFMA B-fragment layout, bf16 hi/lo -----------------------
// step s (0..99): t5 = s>>2, ci = (s&3)*32 + quad*8 + j; nt 0..15.
__global__ __launch_bounds__(256) void k_cvtw4(const float* __restrict__ w4,
                                               unsigned short* __restrict__ w4h,
                                               unsigned short* __restrict__ w4l) {
    int t = blockIdx.x * 256 + threadIdx.x;   // grid exact: 400*256 = 102,400
    int s = t >> 10, rem = t & 1023;
    int nt = rem >> 6, lane = rem & 63;
    int quad = lane >> 4, n = lane & 15;
    int t5 = s >> 2, cib = s & 3;
#pragma unroll
    for (int j = 0; j < 8; j++) {
        int ci = cib * 32 + quad * 8 + j;
        float v = w4[(size_t)(t5 * 128 + ci) * 256 + nt * 16 + n];
        unsigned short h = f2bf(v);
        w4h[(size_t)t * 8 + j] = h;
        w4l[(size_t)t * 8 + j] = f2bf(v - bf2f(h));
    }
}

// ---- layer 3: MFMA conv 5x5 64->128 + ELU + maxpool4 -> 36^2 ----------------
__global__ __launch_bounds__(256) void k_l3(const unsigned short* __restrict__ y2h,
                                            const unsigned short* __restrict__ y2l,
                                            const unsigned char* __restrict__ m2,
                                            const unsigned short* __restrict__ w3h,
                                            const unsigned short* __restrict__ w3l,
                                            float* __restrict__ y3,
                                            unsigned char* __restrict__ m3) {
    __shared__ uint4 win_h4[512];
    __shared__ uint4 win_l4[512];
    __shared__ unsigned char sm[16];
    int b = blockIdx.x;                  // 0..1295
    int ppr = b / S3, ppc = b % S3;
    int r0 = ppr * 4 - 2, c0 = ppc * 4 - 2;
    int tid = threadIdx.x;
    for (int k = tid; k < 512; k += 256) {
        int cellk = k >> 3, q = k & 7;
        int gr = r0 + (cellk >> 3), gc = c0 + (cellk & 7);
        uint4 vh = make_uint4(0, 0, 0, 0), vl = vh;
        if (gr >= 0 && gr < S2 && gc >= 0 && gc < S2) {
            vh = ((const uint4*)y2h)[(size_t)(gr * S2 + gc) * 8 + q];
            vl = ((const uint4*)y2l)[(size_t)(gr * S2 + gc) * 8 + q];
        }
        win_h4[k] = vh;
        win_l4[k] = vl;
    }
    if (tid < 16) sm[tid] = m2[(ppr * 4 + (tid >> 2)) * S2 + ppc * 4 + (tid & 3)];
    __syncthreads();
    const bf16x8* winh8 = (const bf16x8*)win_h4;
    const bf16x8* winl8 = (const bf16x8*)win_l4;
    const bf16x8* w3h8 = (const bf16x8*)w3h;
    const bf16x8* w3l8 = (const bf16x8*)w3l;
    int wv = tid >> 6, lane = tid & 63;
    int quad = lane >> 4, n = lane & 15;
    int cellr = n >> 2, cellc = n & 3;
    f32x4 acc0 = {0.f, 0.f, 0.f, 0.f}, acc1 = {0.f, 0.f, 0.f, 0.f};
#pragma unroll 2
    for (int s = 0; s < 50; s++) {
        int t5 = s >> 1, cib = s & 1;
        int ky = t5 / 5, kx = t5 % 5;
        int aidx = ((cellr + ky) * 8 + (cellc + kx)) * 8 + cib * 4 + quad;
        bf16x8 ah = winh8[aidx];
        bf16x8 al = winl8[aidx];
        int bbase = (s * 8 + wv * 2) * 64 + lane;
        bf16x8 bh0 = w3h8[bbase], bl0 = w3l8[bbase];
        bf16x8 bh1 = w3h8[bbase + 64], bl1 = w3l8[bbase + 64];
        acc0 = __builtin_amdgcn_mfma_f32_16x16x32_bf16(ah, bh0, acc0, 0, 0, 0);
        acc0 = __builtin_amdgcn_mfma_f32_16x16x32_bf16(al, bh0, acc0, 0, 0, 0);
        acc0 = __builtin_amdgcn_mfma_f32_16x16x32_bf16(ah, bl0, acc0, 0, 0, 0);
        acc1 = __builtin_amdgcn_mfma_f32_16x16x32_bf16(ah, bh1, acc1, 0, 0, 0);
        acc1 = __builtin_amdgcn_mfma_f32_16x16x32_bf16(al, bh1, acc1, 0, 0, 0);
        acc1 = __builtin_amdgcn_mfma_f32_16x16x32_bf16(ah, bl1, acc1, 0, 0, 0);
    }
    bool anyv = false;
#pragma unroll
    for (int i = 0; i < 16; i++) anyv |= (sm[i] != 0);
    float mv0 = NEGF, mv1 = NEGF;
#pragma unroll
    for (int r = 0; r < 4; r++) {
        int cell = quad * 4 + r;
        if (sm[cell]) {
            mv0 = fmaxf(mv0, acc0[r]);
            mv1 = fmaxf(mv1, acc1[r]);
        }
    }
    mv0 = fmaxf(mv0, __shfl_xor(mv0, 16, 64));
    mv0 = fmaxf(mv0, __shfl_xor(mv0, 32, 64));
    mv1 = fmaxf(mv1, __shfl_xor(mv1, 16, 64));
    mv1 = fmaxf(mv1, __shfl_xor(mv1, 32, 64));
    if (quad == 0) {
        int cob = wv * 32;
        y3[(size_t)b * 128 + cob + n] = anyv ? eluf(mv0) : 0.f;
        y3[(size_t)b * 128 + cob + 16 + n] = anyv ? eluf(mv1) : 0.f;
    }
    if (tid == 0) m3[b] = anyv ? 1 : 0;
}

// ---- layer 4: MFMA conv 5x5 128->256 + ELU + maxpool4 -> 9^2 (fused) --------
// One block per pool site (81 blocks, 4 waves); wave wv covers N-tiles
// wv*4..wv*4+3. M-tile = the 16 pool-window cells; K = 25 taps x 128 ci
// = 100 steps. Window 8x8x128 converted f32->bf16 hi/lo in-kernel (32 KB).
// Full K in-block -> gated maxpool + ELU fused; k_p4 eliminated.
__global__ __launch_bounds__(256) void k_l4(const float* __restrict__ y3,
                                            const unsigned char* __restrict__ m3,
                                            const unsigned short* __restrict__ w4h,
                                            const unsigned short* __restrict__ w4l,
                                            float* __restrict__ y4) {
    __shared__ unsigned short winh[64 * 128];   // 16 KB
    __shared__ unsigned short winl[64 * 128];   // 16 KB
    __shared__ unsigned char sm[16];
    int p = blockIdx.x;                  // 0..80
    int ppr = p / S4, ppc = p % S4;
    int r0 = ppr * 4 - 2, c0 = ppc * 4 - 2;
    int tid = threadIdx.x;
    for (int k = tid; k < 2048; k += 256) {     // k = cell*32 + q (q = 4-ci group)
        int cellk = k >> 5, q = k & 31;
        int gr = r0 + (cellk >> 3), gc = c0 + (cellk & 7);
        float4 v = make_float4(0.f, 0.f, 0.f, 0.f);
        if (gr >= 0 && gr < S3 && gc >= 0 && gc < S3)
            v = ((const float4*)y3)[((size_t)gr * S3 + gc) * 32 + q];
        unsigned short h0 = f2bf(v.x), h1 = f2bf(v.y), h2 = f2bf(v.z), h3 = f2bf(v.w);
        unsigned uh0 = (unsigned)h0 | ((unsigned)h1 << 16);
        unsigned uh1 = (unsigned)h2 | ((unsigned)h3 << 16);
        unsigned short l0 = f2bf(v.x - bf2f(h0)), l1 = f2bf(v.y - bf2f(h1));
        unsigned short l2 = f2bf(v.z - bf2f(h2)), l3 = f2bf(v.w - bf2f(h3));
        unsigned ul0 = (unsigned)l0 | ((unsigned)l1 << 16);
        unsigned ul1 = (unsigned)l2 | ((unsigned)l3 << 16);
        ((uint2*)winh)[k] = make_uint2(uh0, uh1);
        ((uint2*)winl)[k] = make_uint2(ul0, ul1);
    }
    if (tid < 16) sm[tid] = m3[(ppr * 4 + (tid >> 2)) * S3 + ppc * 4 + (tid & 3)];
    __syncthreads();
    const bf16x8* winh8 = (const bf16x8*)winh;
    const bf16x8* winl8 = (const bf16x8*)winl;
    const bf16x8* w4h8 = (const bf16x8*)w4h;
    const bf16x8* w4l8 = (const bf16x8*)w4l;
    int wv = tid >> 6, lane = tid & 63;
    int quad = lane >> 4, n = lane & 15;
    int cellr = n >> 2, cellc = n & 3;
    f32x4 acc[4];
#pragma unroll
    for (int i = 0; i < 4; i++) acc[i] = (f32x4){0.f, 0.f, 0.f, 0.f};
#pragma unroll 2
    for (int s = 0; s < 100; s++) {
        int t5 = s >> 2, cib = s & 3;
        int ky = t5 / 5, kx = t5 % 5;
        int aidx = ((cellr + ky) * 8 + (cellc + kx)) * 16 + cib * 4 + quad;
        bf16x8 ah = winh8[aidx];
        bf16x8 al = winl8[aidx];
#pragma unroll
        for (int nti = 0; nti < 4; nti++) {
            int bbase = (s * 16 + wv * 4 + nti) * 64 + lane;
            bf16x8 bh = w4h8[bbase];
            bf16x8 bl = w4l8[bbase];
            acc[nti] = __builtin_amdgcn_mfma_f32_16x16x32_bf16(ah, bh, acc[nti], 0, 0, 0);
            acc[nti] = __builtin_amdgcn_mfma_f32_16x16x32_bf16(al, bh, acc[nti], 0, 0, 0);
            acc[nti] = __builtin_amdgcn_mfma_f32_16x16x32_bf16(ah, bl, acc[nti], 0, 0, 0);
        }
    }
    bool anyv = false;
#pragma unroll
    for (int i = 0; i < 16; i++) anyv |= (sm[i] != 0);
#pragma unroll
    for (int nti = 0; nti < 4; nti++) {
        float m = NEGF;
#pragma unroll
        for (int r = 0; r < 4; r++) {
            int cell = quad * 4 + r;
            if (sm[cell]) m = fmaxf(m, acc[nti][r]);
        }
        m = fmaxf(m, __shfl_xor(m, 16, 64));
        m = fmaxf(m, __shfl_xor(m, 32, 64));
        if (quad == 0)
            y4[(size_t)p * 256 + (wv * 4 + nti) * 16 + n] = anyv ? eluf(m) : 0.f;
    }
}

// ---- fc1: 81 blocks x 256 thr; thread = one NCHW row; coalesced W rows ------
__global__ __launch_bounds__(256) void k_fc1(const float* __restrict__ y4,
                                             const float* __restrict__ fc1_w,
                                             float* __restrict__ h1) {
    __shared__ float wsum[4][32];
    int t = threadIdx.x;
    int i = blockIdx.x * 256 + t;
    int c = i / 81, rem = i % 81;
    float x = y4[(size_t)rem * 256 + c];
    const float4* wr = (const float4*)&fc1_w[(size_t)i * 32];
    float4 w[8];
#pragma unroll
    for (int q = 0; q < 8; q++) w[q] = wr[q];
    int lane = t & 63, wv = t >> 6;
#pragma unroll
    for (int q = 0; q < 8; q++) {
#pragma unroll
        for (int k = 0; k < 4; k++) {
            float v = x * ((&w[q].x)[k]);
            v += __shfl_down(v, 32, 64);
            v += __shfl_down(v, 16, 64);
            v += __shfl_down(v, 8, 64);
            v += __shfl_down(v, 4, 64);
            v += __shfl_down(v, 2, 64);
            v += __shfl_down(v, 1, 64);
            if (lane == 0) wsum[wv][q * 4 + k] = v;
        }
    }
    __syncthreads();
    if (t < 32) {
        float s = wsum[0][t] + wsum[1][t] + wsum[2][t] + wsum[3][t];
        atomicAdd(&h1[t], s);
    }
}

// ---- fc2 + softmax ----------------------------------------------------------
__global__ __launch_bounds__(64) void k_fc2(const float* __restrict__ h1,
                                            const float* __restrict__ fc1_b,
                                            const float* __restrict__ fc2_w,
                                            const float* __restrict__ fc2_b,
                                            float* __restrict__ out) {
    __shared__ float hv[32];
    __shared__ float lg[5];
    int tid = threadIdx.x;
    if (tid < 32) hv[tid] = eluf(h1[tid] + fc1_b[tid]);
    __syncthreads();
    if (tid < 5) {
        float s = fc2_b[tid];
        for (int j = 0; j < 32; j++) s = fmaf(hv[j], fc2_w[j * 5 + tid], s);
        lg[tid] = s;
    }
    __syncthreads();
    if (tid == 0) {
        float m = lg[0];
        for (int k = 1; k < 5; k++) m = fmaxf(m, lg[k]);
        float e[5], sum = 0.f;
        for (int k = 0; k < 5; k++) { e[k] = expf(lg[k] - m); sum += e[k]; }
        for (int k = 0; k < 5; k++) out[k] = e[k] / sum;
    }
}

extern "C" void kernel_launch(void* const* d_in, const int* in_sizes, int n_in,
                              void* d_out, int out_size, void* d_ws, size_t ws_size,
                              hipStream_t stream) {
    const int* coords = (const int*)d_in[0];
    const float* feats = (const float*)d_in[1];
    const float* w1 = (const float*)d_in[2];
    const float* w2 = (const float*)d_in[3];
    const float* w3 = (const float*)d_in[4];
    const float* w4 = (const float*)d_in[5];
    const float* fc1w = (const float*)d_in[6];
    const float* fc1b = (const float*)d_in[7];
    const float* fc2w = (const float*)d_in[8];
    const float* fc2b = (const float*)d_in[9];
    float* out = (float*)d_out;
    char* ws = (char*)d_ws;
    float* x0 = (float*)(ws + OFF_X0);
    unsigned* m0b = (unsigned*)(ws + OFF_M0B);
    float* y1 = (float*)(ws + OFF_Y1);
    unsigned char* m1g = (unsigned char*)(ws + OFF_M1);
    float* y2 = (float*)(ws + OFF_Y2);
    unsigned char* m2g = (unsigned char*)(ws + OFF_M2);
    float* y3 = (float*)(ws + OFF_Y3);
    unsigned char* m3g = (unsigned char*)(ws + OFF_M3);
    float* y4 = (float*)(ws + OFF_Y4);
    float* h1 = (float*)(ws + OFF_H1);
    unsigned short* y2h = (unsigned short*)(ws + OFF_Y2H);
    unsigned short* y2l = (unsigned short*)(ws + OFF_Y2L);
    unsigned short* w3h = (unsigned short*)(ws + OFF_W3H);
    unsigned short* w3l = (unsigned short*)(ws + OFF_W3L);
    unsigned short* w2h = (unsigned short*)(ws + OFF_W2H);
    unsigned short* w2l = (unsigned short*)(ws + OFF_W2L);
    unsigned short* w4h = (unsigned short*)(ws + OFF_W4H);
    unsigned short* w4l = (unsigned short*)(ws + OFF_W4L);
    int P = in_sizes[1];

    hipMemsetAsync(ws + OFF_M0B, 0, 1620000, stream);
    k_zero<<<(P + 255) / 256, 256, 0, stream>>>(coords, x0, P);
    k_scatter<<<(P + 255) / 256, 256, 0, stream>>>(coords, feats, x0, m0b, P);
    k_l1<<<(S1 * S1) / 256, 256, 0, stream>>>(x0, m0b, w1, y1, m1g);
    // converters write into the dead-x0 region: run strictly after k_l1.
    k_cvtw2<<<13, 256, 0, stream>>>(w2, w2h, w2l);
    k_cvtw<<<100, 256, 0, stream>>>(w3, w3h, w3l);
    k_cvtw4<<<400, 256, 0, stream>>>(w4, w4h, w4l);
    k_l2<<<72 * 72, 256, 0, stream>>>(y1, m1g, w2h, w2l, y2, m2g);
    k_cvt<<<(S2 * S2 * 64) / 256, 256, 0, stream>>>(y2, y2h, y2l);
    k_l3<<<S3 * S3, 256, 0, stream>>>(y2h, y2l, m2g, w3h, w3l, y3, m3g);
    k_l4<<<S4 * S4, 256, 0, stream>>>(y3, m3g, w4h, w4l, y4);
    hipMemsetAsync(ws + OFF_H1, 0, 128, stream);
    k_fc1<<<81, 256, 0, stream>>>(y4, fc1w, h1);
    k_fc2<<<1, 64, 0, stream>>>(h1, fc1b, fc2w, fc2b, out);
}